// Round 1
// baseline (740.309 us; speedup 1.0000x reference)
//
#include <hip/hip_runtime.h>
#include <hip/hip_bf16.h>

// Problem constants (from reference setup_inputs)
#define BATCH 16
#define DQ 768
#define NQ 1024      // T*Hp*Wp = 4*16*16
#define NT 64
#define DKV 384
#define NHEAD 12
#define HD 64
#define HD2 32

#define BK 16

// ---------------------------------------------------------------------------
// Kernel 1: kv[b][t][j] = sum_c tokens[b][t][c] * Wkv[c][j]   (j in [0,1536))
// M=64 (t), N=1536, K=384. One block: 64x64 output tile.
// ---------------------------------------------------------------------------
__global__ __launch_bounds__(256) void gemm_kv_k(const float* __restrict__ tokens,
                                                 const float* __restrict__ Wkv,
                                                 float* __restrict__ kv_out) {
    const int b = blockIdx.z;
    const int j0 = blockIdx.x * 64;
    __shared__ float As[BK][64];   // As[kk][m] = tokens[b][m][c0+kk]
    __shared__ float Bs[BK][64];   // Bs[kk][nn] = Wkv[c0+kk][j0+nn]
    const int tid = threadIdx.x;
    const int tx = tid & 15, ty = tid >> 4;
    float acc[4][4] = {};
    const float* tb = tokens + (size_t)b * NT * DKV;
    for (int c0 = 0; c0 < DKV; c0 += BK) {
        {
            // A: transpose-stage. thread: m = tid>>2 (0..63), jq = tid&3
            int m = tid >> 2, jq = tid & 3;
            float4 v = *(const float4*)(tb + (size_t)m * DKV + c0 + jq * 4);
            As[jq * 4 + 0][m] = v.x; As[jq * 4 + 1][m] = v.y;
            As[jq * 4 + 2][m] = v.z; As[jq * 4 + 3][m] = v.w;
            int kk = tid >> 4, n4 = (tid & 15) * 4;
            *(float4*)&Bs[kk][n4] = *(const float4*)(Wkv + (size_t)(c0 + kk) * (2 * DQ) + j0 + n4);
        }
        __syncthreads();
#pragma unroll
        for (int kk = 0; kk < BK; ++kk) {
            float a[4], bb[4];
            *(float4*)a  = *(float4*)&As[kk][ty * 4];
            *(float4*)bb = *(float4*)&Bs[kk][tx * 4];
#pragma unroll
            for (int i = 0; i < 4; ++i)
#pragma unroll
                for (int j = 0; j < 4; ++j)
                    acc[i][j] += a[i] * bb[j];
        }
        __syncthreads();
    }
    float* ob = kv_out + (size_t)b * NT * (2 * DQ);
#pragma unroll
    for (int i = 0; i < 4; ++i)
        *(float4*)(ob + (size_t)(ty * 4 + i) * (2 * DQ) + j0 + tx * 4) = *(float4*)acc[i];
}

// ---------------------------------------------------------------------------
// Kernel 2: q[b][n][j] = sum_c feat[b][c][n] * Wq[c][j]
// A is K-major in global (feat[b][c][n], n contiguous) -> natural staging.
// ---------------------------------------------------------------------------
__global__ __launch_bounds__(256) void gemm_q_k(const float* __restrict__ feat,
                                                const float* __restrict__ Wq,
                                                float* __restrict__ q_out) {
    const int b = blockIdx.z;
    const int n0 = blockIdx.y * 64;
    const int j0 = blockIdx.x * 64;
    __shared__ float As[BK][64];   // As[kk][m] = feat[b][c0+kk][n0+m]
    __shared__ float Bs[BK][64];   // Bs[kk][nn] = Wq[c0+kk][j0+nn]
    const int tid = threadIdx.x;
    const int tx = tid & 15, ty = tid >> 4;
    float acc[4][4] = {};
    const float* fb = feat + (size_t)b * DQ * NQ;
    for (int c0 = 0; c0 < DQ; c0 += BK) {
        {
            int kk = tid >> 4, m4 = (tid & 15) * 4;
            *(float4*)&As[kk][m4] = *(const float4*)(fb + (size_t)(c0 + kk) * NQ + n0 + m4);
            *(float4*)&Bs[kk][m4] = *(const float4*)(Wq + (size_t)(c0 + kk) * DQ + j0 + m4);
        }
        __syncthreads();
#pragma unroll
        for (int kk = 0; kk < BK; ++kk) {
            float a[4], bb[4];
            *(float4*)a  = *(float4*)&As[kk][ty * 4];
            *(float4*)bb = *(float4*)&Bs[kk][tx * 4];
#pragma unroll
            for (int i = 0; i < 4; ++i)
#pragma unroll
                for (int j = 0; j < 4; ++j)
                    acc[i][j] += a[i] * bb[j];
        }
        __syncthreads();
    }
    float* ob = q_out + (size_t)b * NQ * DQ;
#pragma unroll
    for (int i = 0; i < 4; ++i)
        *(float4*)(ob + (size_t)(n0 + ty * 4 + i) * DQ + j0 + tx * 4) = *(float4*)acc[i];
}

// ---------------------------------------------------------------------------
// Kernel 3: attention for one (b, h, 64 q-rows). RoPE applied to staged Q and K
// tiles in LDS. Output overwrites q in place (row/head-local dependency).
// ---------------------------------------------------------------------------
__global__ __launch_bounds__(256) void attn_k(const float* __restrict__ kv,
                                              float* __restrict__ q) {
    const int qt = blockIdx.x, h = blockIdx.y, b = blockIdx.z;
    const int n0 = qt * 64;
    __shared__ float Qs[64][65];
    __shared__ float Ks[64][65];
    __shared__ float Vs[64][65];
    __shared__ float Ps[64][65];
    const int tid = threadIdx.x;
    const int tx = tid & 15, ty = tid >> 4;

    // stage K, V (64 x 64), and Q tile (64 x 64) -- scalar LDS writes (pad 65)
    {
        int r = tid >> 4, c4 = (tid & 15) * 4;
        const float* kvb = kv + (size_t)b * NT * (2 * DQ);
        const float* qb = q + ((size_t)b * NQ + n0) * DQ + h * HD;
        for (int rr = 0; rr < 64; rr += 16) {
            float4 kvl = *(const float4*)(kvb + (size_t)(rr + r) * (2 * DQ) + h * HD + c4);
            Ks[rr + r][c4 + 0] = kvl.x; Ks[rr + r][c4 + 1] = kvl.y;
            Ks[rr + r][c4 + 2] = kvl.z; Ks[rr + r][c4 + 3] = kvl.w;
            float4 vvl = *(const float4*)(kvb + (size_t)(rr + r) * (2 * DQ) + DQ + h * HD + c4);
            Vs[rr + r][c4 + 0] = vvl.x; Vs[rr + r][c4 + 1] = vvl.y;
            Vs[rr + r][c4 + 2] = vvl.z; Vs[rr + r][c4 + 3] = vvl.w;
            float4 qvl = *(const float4*)(qb + (size_t)(rr + r) * DQ + c4);
            Qs[rr + r][c4 + 0] = qvl.x; Qs[rr + r][c4 + 1] = qvl.y;
            Qs[rr + r][c4 + 2] = qvl.z; Qs[rr + r][c4 + 3] = qvl.w;
        }
    }
    __syncthreads();

    // RoPE in LDS: pairs (d, d+32), angle = pos * 10000^(-d/32)
    for (int f = tid; f < 64 * HD2; f += 256) {
        int t = f >> 5, d = f & 31;
        float inv = powf(10000.0f, -(float)d / 32.0f);
        {
            float ang = (float)t * inv;
            float c = cosf(ang), s = sinf(ang);
            float v0 = Ks[t][d], v1 = Ks[t][d + HD2];
            Ks[t][d] = v0 * c - v1 * s;
            Ks[t][d + HD2] = v1 * c + v0 * s;
        }
        {
            float ang = (float)(n0 + t) * inv;
            float c = cosf(ang), s = sinf(ang);
            float v0 = Qs[t][d], v1 = Qs[t][d + HD2];
            Qs[t][d] = v0 * c - v1 * s;
            Qs[t][d + HD2] = v1 * c + v0 * s;
        }
    }
    __syncthreads();

    // scores[qr][t] = sum_d Qs[qr][d]*Ks[t][d]
    float sc[4][4] = {};
#pragma unroll 8
    for (int d = 0; d < HD; ++d) {
        float qv[4], kvv[4];
#pragma unroll
        for (int i = 0; i < 4; ++i) qv[i] = Qs[ty * 4 + i][d];
#pragma unroll
        for (int j = 0; j < 4; ++j) kvv[j] = Ks[tx * 4 + j][d];
#pragma unroll
        for (int i = 0; i < 4; ++i)
#pragma unroll
            for (int j = 0; j < 4; ++j)
                sc[i][j] += qv[i] * kvv[j];
    }

    // softmax over t (spread across the 16-lane tx group)
    const float scale = 0.125f;  // hd^-0.5
#pragma unroll
    for (int i = 0; i < 4; ++i) {
        float m = -1e30f;
#pragma unroll
        for (int j = 0; j < 4; ++j) { sc[i][j] *= scale; m = fmaxf(m, sc[i][j]); }
        for (int off = 1; off < 16; off <<= 1) m = fmaxf(m, __shfl_xor(m, off));
        float s = 0.f;
#pragma unroll
        for (int j = 0; j < 4; ++j) { sc[i][j] = __expf(sc[i][j] - m); s += sc[i][j]; }
        for (int off = 1; off < 16; off <<= 1) s += __shfl_xor(s, off);
        float invs = 1.0f / s;
#pragma unroll
        for (int j = 0; j < 4; ++j) Ps[ty * 4 + i][tx * 4 + j] = sc[i][j] * invs;
    }
    __syncthreads();

    // out[qr][d] = sum_t Ps[qr][t] * Vs[t][d]
    float o[4][4] = {};
#pragma unroll 8
    for (int t = 0; t < NT; ++t) {
        float pv[4], vv[4];
#pragma unroll
        for (int i = 0; i < 4; ++i) pv[i] = Ps[ty * 4 + i][t];
#pragma unroll
        for (int j = 0; j < 4; ++j) vv[j] = Vs[t][tx * 4 + j];
#pragma unroll
        for (int i = 0; i < 4; ++i)
#pragma unroll
            for (int j = 0; j < 4; ++j)
                o[i][j] += pv[i] * vv[j];
    }

    // write back in place over q (this block's rows / head slice only)
    float* qo = q + ((size_t)b * NQ + n0) * DQ + h * HD;
#pragma unroll
    for (int i = 0; i < 4; ++i)
        *(float4*)(qo + (size_t)(ty * 4 + i) * DQ + tx * 4) = *(float4*)o[i];
}

// ---------------------------------------------------------------------------
// Kernel 4: out[b][d][n] = feat[b][d][n] + bout[d] + sum_j ao[b][n][j]*Wout[j][d]
// Transposed write via LDS bounce.
// ---------------------------------------------------------------------------
__global__ __launch_bounds__(256) void gemm_out_k(const float* __restrict__ ao,
                                                  const float* __restrict__ Wout,
                                                  const float* __restrict__ bout,
                                                  const float* __restrict__ feat,
                                                  float* __restrict__ out) {
    const int b = blockIdx.z;
    const int n0 = blockIdx.y * 64;
    const int d0 = blockIdx.x * 64;
    __shared__ float As[BK][64];    // As[kk][m] = ao[b][n0+m][j0+kk]
    __shared__ float Bs[BK][64];    // Bs[kk][nn] = Wout[j0+kk][d0+nn]
    __shared__ float Cs[64][65];    // Cs[n_local][d_local]
    const int tid = threadIdx.x;
    const int tx = tid & 15, ty = tid >> 4;
    float acc[4][4] = {};
    const float* ab = ao + (size_t)b * NQ * DQ;
    for (int j0 = 0; j0 < DQ; j0 += BK) {
        {
            int m = tid >> 2, jq = tid & 3;
            float4 v = *(const float4*)(ab + (size_t)(n0 + m) * DQ + j0 + jq * 4);
            As[jq * 4 + 0][m] = v.x; As[jq * 4 + 1][m] = v.y;
            As[jq * 4 + 2][m] = v.z; As[jq * 4 + 3][m] = v.w;
            int kk = tid >> 4, n4 = (tid & 15) * 4;
            *(float4*)&Bs[kk][n4] = *(const float4*)(Wout + (size_t)(j0 + kk) * DQ + d0 + n4);
        }
        __syncthreads();
#pragma unroll
        for (int kk = 0; kk < BK; ++kk) {
            float a[4], bb[4];
            *(float4*)a  = *(float4*)&As[kk][ty * 4];
            *(float4*)bb = *(float4*)&Bs[kk][tx * 4];
#pragma unroll
            for (int i = 0; i < 4; ++i)
#pragma unroll
                for (int j = 0; j < 4; ++j)
                    acc[i][j] += a[i] * bb[j];
        }
        __syncthreads();
    }
    // bounce through LDS for transposed coalesced write
#pragma unroll
    for (int i = 0; i < 4; ++i)
#pragma unroll
        for (int j = 0; j < 4; ++j)
            Cs[ty * 4 + i][tx * 4 + j] = acc[i][j];
    __syncthreads();
    const int nn = tid & 63;
    for (int dd = tid >> 6; dd < 64; dd += 4) {
        size_t idx = ((size_t)b * DQ + d0 + dd) * NQ + n0 + nn;
        out[idx] = feat[idx] + Cs[nn][dd] + bout[d0 + dd];
    }
}

// ---------------------------------------------------------------------------
extern "C" void kernel_launch(void* const* d_in, const int* in_sizes, int n_in,
                              void* d_out, int out_size, void* d_ws, size_t ws_size,
                              hipStream_t stream) {
    const float* feat   = (const float*)d_in[0];
    const float* tokens = (const float*)d_in[1];
    const float* Wq     = (const float*)d_in[2];
    const float* Wkv    = (const float*)d_in[3];
    const float* Wout   = (const float*)d_in[4];
    const float* bout   = (const float*)d_in[5];
    float* out = (float*)d_out;

    float* ws_q  = (float*)d_ws;                       // [B][NQ][DQ]  = 12.58M floats
    float* ws_kv = ws_q + (size_t)BATCH * NQ * DQ;     // [B][NT][2*DQ] = 1.57M floats

    gemm_kv_k<<<dim3(24, 1, BATCH), 256, 0, stream>>>(tokens, Wkv, ws_kv);
    gemm_q_k<<<dim3(DQ / 64, NQ / 64, BATCH), 256, 0, stream>>>(feat, Wq, ws_q);
    attn_k<<<dim3(NQ / 64, NHEAD, BATCH), 256, 0, stream>>>(ws_kv, ws_q);
    gemm_out_k<<<dim3(DQ / 64, NQ / 64, BATCH), 256, 0, stream>>>(ws_q, Wout, bout, feat, out);
}

// Round 5
// 284.603 us; speedup vs baseline: 2.6012x; 2.6012x over previous
//
#include <hip/hip_runtime.h>
#include <stdint.h>

#define BATCH 16
#define DQ 768
#define NQ 1024      // T*Hp*Wp
#define NT 64
#define DKV 384
#define NHEAD 12
#define HD 64
#define HD2 32

typedef __attribute__((ext_vector_type(8))) short bf16x8;
typedef __attribute__((ext_vector_type(4))) float f32x4;

__device__ __forceinline__ unsigned short f2bf(float f) {
    unsigned u = __float_as_uint(f);
    u += 0x7fff + ((u >> 16) & 1);          // RNE (inputs finite)
    return (unsigned short)(u >> 16);
}
__device__ __forceinline__ float bf2f(unsigned short h) {
    return __uint_as_float((unsigned)h << 16);
}

__device__ __forceinline__ void gload_lds16(const void* g, void* l) {
    __builtin_amdgcn_global_load_lds(
        (const __attribute__((address_space(1))) unsigned int*)g,
        (__attribute__((address_space(3))) unsigned int*)l, 16, 0, 0);
}

// ---------------------------------------------------------------------------
// Transpose + f32->bf16: featT[b][n][c] = feat[b][c][n]
// ---------------------------------------------------------------------------
__global__ __launch_bounds__(256) void conv_feat_k(const float* __restrict__ feat,
                                                   unsigned short* __restrict__ featT) {
    const int b = blockIdx.z;
    const int n0 = blockIdx.x * 64;
    const int c0 = blockIdx.y * 64;
    __shared__ float T[64][65];
    const int tid = threadIdx.x;
    const int r = tid >> 4, c4 = (tid & 15) * 4;
    const float* fb = feat + (size_t)b * DQ * NQ + (size_t)c0 * NQ + n0;
    for (int rr = 0; rr < 64; rr += 16) {
        float4 v = *(const float4*)(fb + (size_t)(rr + r) * NQ + c4);
        T[rr + r][c4 + 0] = v.x; T[rr + r][c4 + 1] = v.y;
        T[rr + r][c4 + 2] = v.z; T[rr + r][c4 + 3] = v.w;
    }
    __syncthreads();
    unsigned short* ob = featT + ((size_t)b * NQ + n0) * DQ + c0;
    for (int rr = 0; rr < 64; rr += 16) {
        int dr = rr + r;   // local n
        ushort4 w;
        w.x = f2bf(T[c4 + 0][dr]); w.y = f2bf(T[c4 + 1][dr]);
        w.z = f2bf(T[c4 + 2][dr]); w.w = f2bf(T[c4 + 3][dr]);
        *(ushort4*)(ob + (size_t)dr * DQ + c4) = w;
    }
}

// ---------------------------------------------------------------------------
// Transpose + f32->bf16 for both weights: WqT[j][c]=Wq[c][j], WoutT[d][j]=Wout[j][d]
// ---------------------------------------------------------------------------
__global__ __launch_bounds__(256) void conv_w_k(const float* __restrict__ Wq,
                                                const float* __restrict__ Wout,
                                                unsigned short* __restrict__ WqT,
                                                unsigned short* __restrict__ WoutT) {
    const float* src = blockIdx.z ? Wout : Wq;
    unsigned short* dst = blockIdx.z ? WoutT : WqT;
    const int r0 = blockIdx.x * 64;   // src row tile
    const int c0 = blockIdx.y * 64;   // src col tile
    __shared__ float T[64][65];
    const int tid = threadIdx.x;
    const int r = tid >> 4, c4 = (tid & 15) * 4;
    for (int rr = 0; rr < 64; rr += 16) {
        float4 v = *(const float4*)(src + (size_t)(r0 + rr + r) * DQ + c0 + c4);
        T[rr + r][c4 + 0] = v.x; T[rr + r][c4 + 1] = v.y;
        T[rr + r][c4 + 2] = v.z; T[rr + r][c4 + 3] = v.w;
    }
    __syncthreads();
    for (int rr = 0; rr < 64; rr += 16) {
        int dr = rr + r;
        ushort4 w;
        w.x = f2bf(T[c4 + 0][dr]); w.y = f2bf(T[c4 + 1][dr]);
        w.z = f2bf(T[c4 + 2][dr]); w.w = f2bf(T[c4 + 3][dr]);
        *(ushort4*)(dst + (size_t)(c0 + dr) * DQ + r0 + c4) = w;
    }
}

// ---------------------------------------------------------------------------
// kv = tokens @ Wkv  (f32, small: 1.2 GF)
// ---------------------------------------------------------------------------
__global__ __launch_bounds__(256) void gemm_kv_k(const float* __restrict__ tokens,
                                                 const float* __restrict__ Wkv,
                                                 float* __restrict__ kv_out) {
    const int b = blockIdx.z;
    const int j0 = blockIdx.x * 64;
    __shared__ float As[16][64];
    __shared__ float Bs[16][64];
    const int tid = threadIdx.x;
    const int tx = tid & 15, ty = tid >> 4;
    float acc[4][4] = {};
    const float* tb = tokens + (size_t)b * NT * DKV;
    for (int c0 = 0; c0 < DKV; c0 += 16) {
        {
            int m = tid >> 2, jq = tid & 3;
            float4 v = *(const float4*)(tb + (size_t)m * DKV + c0 + jq * 4);
            As[jq * 4 + 0][m] = v.x; As[jq * 4 + 1][m] = v.y;
            As[jq * 4 + 2][m] = v.z; As[jq * 4 + 3][m] = v.w;
            int kk = tid >> 4, n4 = (tid & 15) * 4;
            *(float4*)&Bs[kk][n4] = *(const float4*)(Wkv + (size_t)(c0 + kk) * (2 * DQ) + j0 + n4);
        }
        __syncthreads();
#pragma unroll
        for (int kk = 0; kk < 16; ++kk) {
            float a[4], bb[4];
            *(float4*)a  = *(float4*)&As[kk][ty * 4];
            *(float4*)bb = *(float4*)&Bs[kk][tx * 4];
#pragma unroll
            for (int i = 0; i < 4; ++i)
#pragma unroll
                for (int j = 0; j < 4; ++j)
                    acc[i][j] += a[i] * bb[j];
        }
        __syncthreads();
    }
    float* ob = kv_out + (size_t)b * NT * (2 * DQ);
#pragma unroll
    for (int i = 0; i < 4; ++i)
        *(float4*)(ob + (size_t)(ty * 4 + i) * (2 * DQ) + j0 + tx * 4) = *(float4*)acc[i];
}

// ---------------------------------------------------------------------------
// MFMA GEMM: q[b][n][j] = featT[b][n][:] . WqT[j][:]   (both bf16 K-contiguous)
// 128x128 tile, BK=32, 4 waves each 64x64. global_load_lds w/ 4-slot swizzle.
// ---------------------------------------------------------------------------
__global__ __launch_bounds__(256) void gemm_q_mfma(const unsigned short* __restrict__ At,
                                                   const unsigned short* __restrict__ Bt,
                                                   unsigned short* __restrict__ C) {
    const int b = blockIdx.z;
    const int m0 = blockIdx.x * 128;
    const int n0 = blockIdx.y * 128;
    __shared__ __align__(16) unsigned short ldsA[128 * 32];
    __shared__ __align__(16) unsigned short ldsB[128 * 32];
    const int tid = threadIdx.x;
    const int lane = tid & 63;
    const int wm = ((tid >> 7) & 1) * 64;      // wave m offset
    const int wn = ((tid >> 6) & 1) * 64;      // wave n offset
    const int fr = lane & 15;
    const int fg = lane >> 4;
    const int pslot = (fg ^ ((fr >> 1) & 3)) * 16;   // physical 16B slot for frag reads
    const int wbase = (tid & 192) * 16;              // wave-uniform LDS byte base
    f32x4 acc[4][4] = {};

    const unsigned short* Ab = At + (size_t)b * NQ * DQ + (size_t)m0 * DQ;
    const unsigned short* Bb = Bt + (size_t)n0 * DQ;
    const int srow_lo = tid >> 2;      // staging row for inst 0 (inst 1: +64)
    const int sslot = tid & 3;

    for (int k0 = 0; k0 < DQ; k0 += 32) {
#pragma unroll
        for (int i = 0; i < 2; ++i) {
            int row = i * 64 + srow_lo;
            int sl = sslot ^ ((row >> 1) & 3);
            gload_lds16(Ab + (size_t)row * DQ + k0 + sl * 8,
                        (char*)ldsA + i * 4096 + wbase);
            gload_lds16(Bb + (size_t)row * DQ + k0 + sl * 8,
                        (char*)ldsB + i * 4096 + wbase);
        }
        __syncthreads();
        bf16x8 af[4], bfr[4];
#pragma unroll
        for (int f = 0; f < 4; ++f) {
            af[f]  = *(const bf16x8*)((const char*)ldsA + (wm + f * 16 + fr) * 64 + pslot);
            bfr[f] = *(const bf16x8*)((const char*)ldsB + (wn + f * 16 + fr) * 64 + pslot);
        }
#pragma unroll
        for (int i = 0; i < 4; ++i)
#pragma unroll
            for (int j = 0; j < 4; ++j)
                acc[i][j] = __builtin_amdgcn_mfma_f32_16x16x32_bf16(af[i], bfr[j], acc[i][j], 0, 0, 0);
        __syncthreads();
    }
    // C/D layout: col = lane&15, row = (lane>>4)*4 + reg   [m89/m91]
    unsigned short* Cb = C + (size_t)b * NQ * DQ;
#pragma unroll
    for (int i = 0; i < 4; ++i)
#pragma unroll
        for (int j = 0; j < 4; ++j) {
            int rbase = m0 + wm + i * 16 + fg * 4;
            int col = n0 + wn + j * 16 + fr;
#pragma unroll
            for (int r = 0; r < 4; ++r)
                Cb[(size_t)(rbase + r) * DQ + col] = f2bf(acc[i][j][r]);
        }
}

// ---------------------------------------------------------------------------
// MFMA GEMM (transposed output, fused residual+bias):
// out[b][d][n] = WoutT[d][:] . ao[b][n][:] + feat[b][d][n] + bout[d]
// ---------------------------------------------------------------------------
__global__ __launch_bounds__(256) void gemm_out_mfma(const unsigned short* __restrict__ At,
                                                     const unsigned short* __restrict__ Bt,
                                                     const float* __restrict__ feat,
                                                     const float* __restrict__ bout,
                                                     float* __restrict__ out) {
    const int b = blockIdx.z;
    const int m0 = blockIdx.x * 128;   // d
    const int n0 = blockIdx.y * 128;   // n
    __shared__ __align__(16) unsigned short ldsA[128 * 32];
    __shared__ __align__(16) unsigned short ldsB[128 * 32];
    const int tid = threadIdx.x;
    const int lane = tid & 63;
    const int wm = ((tid >> 7) & 1) * 64;
    const int wn = ((tid >> 6) & 1) * 64;
    const int fr = lane & 15;
    const int fg = lane >> 4;
    const int pslot = (fg ^ ((fr >> 1) & 3)) * 16;
    const int wbase = (tid & 192) * 16;
    f32x4 acc[4][4] = {};

    const unsigned short* Ab = At + (size_t)m0 * DQ;                          // WoutT (shared across b)
    const unsigned short* Bb = Bt + (size_t)b * NQ * DQ + (size_t)n0 * DQ;    // ao
    const int srow_lo = tid >> 2;
    const int sslot = tid & 3;

    for (int k0 = 0; k0 < DQ; k0 += 32) {
#pragma unroll
        for (int i = 0; i < 2; ++i) {
            int row = i * 64 + srow_lo;
            int sl = sslot ^ ((row >> 1) & 3);
            gload_lds16(Ab + (size_t)row * DQ + k0 + sl * 8,
                        (char*)ldsA + i * 4096 + wbase);
            gload_lds16(Bb + (size_t)row * DQ + k0 + sl * 8,
                        (char*)ldsB + i * 4096 + wbase);
        }
        __syncthreads();
        bf16x8 af[4], bfr[4];
#pragma unroll
        for (int f = 0; f < 4; ++f) {
            af[f]  = *(const bf16x8*)((const char*)ldsA + (wm + f * 16 + fr) * 64 + pslot);
            bfr[f] = *(const bf16x8*)((const char*)ldsB + (wn + f * 16 + fr) * 64 + pslot);
        }
#pragma unroll
        for (int i = 0; i < 4; ++i)
#pragma unroll
            for (int j = 0; j < 4; ++j)
                acc[i][j] = __builtin_amdgcn_mfma_f32_16x16x32_bf16(af[i], bfr[j], acc[i][j], 0, 0, 0);
        __syncthreads();
    }
    float* ob = out + (size_t)b * DQ * NQ;
    const float* fb = feat + (size_t)b * DQ * NQ;
#pragma unroll
    for (int i = 0; i < 4; ++i)
#pragma unroll
        for (int j = 0; j < 4; ++j) {
            int dbase = m0 + wm + i * 16 + fg * 4;
            int n = n0 + wn + j * 16 + fr;
#pragma unroll
            for (int r = 0; r < 4; ++r) {
                int d = dbase + r;
                size_t idx = (size_t)d * NQ + n;
                ob[idx] = acc[i][j][r] + fb[idx] + bout[d];
            }
        }
}

// ---------------------------------------------------------------------------
// Attention per (b, h, 64 q-rows). q is bf16; kv f32. RoPE in LDS.
// Writes ao (bf16) IN PLACE over q (block-local rows/head slice).
// ---------------------------------------------------------------------------
__global__ __launch_bounds__(256) void attn_k(const float* __restrict__ kv,
                                              unsigned short* __restrict__ q) {
    const int qt = blockIdx.x, h = blockIdx.y, b = blockIdx.z;
    const int n0 = qt * 64;
    __shared__ float Qs[64][65];   // reused as P after scores
    __shared__ float Ks[64][65];
    __shared__ float Vs[64][65];
    const int tid = threadIdx.x;
    const int tx = tid & 15, ty = tid >> 4;

    {
        int r = tid >> 4, c4 = (tid & 15) * 4;
        const float* kvb = kv + (size_t)b * NT * (2 * DQ) + h * HD;
        const unsigned short* qb = q + ((size_t)b * NQ + n0) * DQ + h * HD;
        for (int rr = 0; rr < 64; rr += 16) {
            float4 kl = *(const float4*)(kvb + (size_t)(rr + r) * (2 * DQ) + c4);
            Ks[rr + r][c4 + 0] = kl.x; Ks[rr + r][c4 + 1] = kl.y;
            Ks[rr + r][c4 + 2] = kl.z; Ks[rr + r][c4 + 3] = kl.w;
            float4 vl = *(const float4*)(kvb + (size_t)(rr + r) * (2 * DQ) + DQ + c4);
            Vs[rr + r][c4 + 0] = vl.x; Vs[rr + r][c4 + 1] = vl.y;
            Vs[rr + r][c4 + 2] = vl.z; Vs[rr + r][c4 + 3] = vl.w;
            ushort4 ql = *(const ushort4*)(qb + (size_t)(rr + r) * DQ + c4);
            Qs[rr + r][c4 + 0] = bf2f(ql.x); Qs[rr + r][c4 + 1] = bf2f(ql.y);
            Qs[rr + r][c4 + 2] = bf2f(ql.z); Qs[rr + r][c4 + 3] = bf2f(ql.w);
        }
    }
    __syncthreads();

    // RoPE pairs (d, d+32): angle = pos * 10000^(-d/32)
    for (int f = tid; f < 64 * HD2; f += 256) {
        int t = f >> 5, d = f & 31;
        float inv = exp2f((float)d * -0.41524101186092029f);  // -log2(1e4)/32
        float s1, c1; __sincosf((float)t * inv, &s1, &c1);
        float v0 = Ks[t][d], v1 = Ks[t][d + HD2];
        Ks[t][d] = v0 * c1 - v1 * s1;
        Ks[t][d + HD2] = v1 * c1 + v0 * s1;
        float s2, c2; __sincosf((float)(n0 + t) * inv, &s2, &c2);
        float w0 = Qs[t][d], w1 = Qs[t][d + HD2];
        Qs[t][d] = w0 * c2 - w1 * s2;
        Qs[t][d + HD2] = w1 * c2 + w0 * s2;
    }
    __syncthreads();

    // scores[qr][t]
    float sc[4][4] = {};
#pragma unroll 8
    for (int d = 0; d < HD; ++d) {
        float qv[4], kvv[4];
#pragma unroll
        for (int i = 0; i < 4; ++i) qv[i] = Qs[ty * 4 + i][d];
#pragma unroll
        for (int j = 0; j < 4; ++j) kvv[j] = Ks[tx * 4 + j][d];
#pragma unroll
        for (int i = 0; i < 4; ++i)
#pragma unroll
            for (int j = 0; j < 4; ++j)
                sc[i][j] += qv[i] * kvv[j];
    }
    __syncthreads();   // all Qs reads done; safe to reuse as P

    const float scale = 0.125f;
#pragma unroll
    for (int i = 0; i < 4; ++i) {
        float m = -1e30f;
#pragma unroll
        for (int j = 0; j < 4; ++j) { sc[i][j] *= scale; m = fmaxf(m, sc[i][j]); }
        for (int off = 1; off < 16; off <<= 1) m = fmaxf(m, __shfl_xor(m, off));
        float s = 0.f;
#pragma unroll
        for (int j = 0; j < 4; ++j) { sc[i][j] = __expf(sc[i][j] - m); s += sc[i][j]; }
        for (int off = 1; off < 16; off <<= 1) s += __shfl_xor(s, off);
        float invs = 1.0f / s;
#pragma unroll
        for (int j = 0; j < 4; ++j) Qs[ty * 4 + i][tx * 4 + j] = sc[i][j] * invs;
    }
    __syncthreads();

    float o[4][4] = {};
#pragma unroll 8
    for (int t = 0; t < NT; ++t) {
        float pv[4], vv[4];
#pragma unroll
        for (int i = 0; i < 4; ++i) pv[i] = Qs[ty * 4 + i][t];
#pragma unroll
        for (int j = 0; j < 4; ++j) vv[j] = Vs[t][tx * 4 + j];
#pragma unroll
        for (int i = 0; i < 4; ++i)
#pragma unroll
            for (int j = 0; j < 4; ++j)
                o[i][j] += pv[i] * vv[j];
    }

    unsigned short* aob = q + ((size_t)b * NQ + n0) * DQ + h * HD;
#pragma unroll
    for (int i = 0; i < 4; ++i) {
        ushort4 w;
        w.x = f2bf(o[i][0]); w.y = f2bf(o[i][1]);
        w.z = f2bf(o[i][2]); w.w = f2bf(o[i][3]);
        *(ushort4*)(aob + (size_t)(ty * 4 + i) * DQ + tx * 4) = w;
    }
}

// ---------------------------------------------------------------------------
extern "C" void kernel_launch(void* const* d_in, const int* in_sizes, int n_in,
                              void* d_out, int out_size, void* d_ws, size_t ws_size,
                              hipStream_t stream) {
    const float* feat   = (const float*)d_in[0];
    const float* tokens = (const float*)d_in[1];
    const float* Wq     = (const float*)d_in[2];
    const float* Wkv    = (const float*)d_in[3];
    const float* Wout   = (const float*)d_in[4];
    const float* bout   = (const float*)d_in[5];
    float* out = (float*)d_out;

    float* ws_kv = (float*)d_ws;                                        // [B][NT][2*DQ] f32
    unsigned short* ws_featT = (unsigned short*)(ws_kv + (size_t)BATCH * NT * 2 * DQ);  // [B][NQ][DQ] bf16
    unsigned short* ws_q     = ws_featT + (size_t)BATCH * NQ * DQ;      // [B][NQ][DQ] bf16 (q, then ao in place)
    unsigned short* ws_WqT   = ws_q + (size_t)BATCH * NQ * DQ;          // [DQ][DQ] bf16
    unsigned short* ws_WoutT = ws_WqT + (size_t)DQ * DQ;                // [DQ][DQ] bf16

    conv_w_k<<<dim3(12, 12, 2), 256, 0, stream>>>(Wq, Wout, ws_WqT, ws_WoutT);
    conv_feat_k<<<dim3(16, 12, BATCH), 256, 0, stream>>>(feat, ws_featT);
    gemm_kv_k<<<dim3(24, 1, BATCH), 256, 0, stream>>>(tokens, Wkv, ws_kv);
    gemm_q_mfma<<<dim3(8, 6, BATCH), 256, 0, stream>>>(ws_featT, ws_WqT, ws_q);
    attn_k<<<dim3(16, 12, BATCH), 256, 0, stream>>>(ws_kv, ws_q);
    gemm_out_mfma<<<dim3(6, 8, BATCH), 256, 0, stream>>>(ws_WoutT, ws_q, feat, bout, out);
}

// Round 6
// 230.494 us; speedup vs baseline: 3.2118x; 1.2348x over previous
//
#include <hip/hip_runtime.h>
#include <stdint.h>

#define BATCH 16
#define DQ 768
#define NQ 1024      // T*Hp*Wp
#define NT 64
#define DKV 384
#define NHEAD 12
#define HD 64
#define HD2 32

typedef __attribute__((ext_vector_type(8))) short bf16x8;
typedef __attribute__((ext_vector_type(4))) float f32x4;

__device__ __forceinline__ unsigned short f2bf(float f) {
    unsigned u = __float_as_uint(f);
    u += 0x7fff + ((u >> 16) & 1);          // RNE (inputs finite)
    return (unsigned short)(u >> 16);
}
__device__ __forceinline__ float bf2f(unsigned short h) {
    return __uint_as_float((unsigned)h << 16);
}

__device__ __forceinline__ void gload_lds16(const void* g, void* l) {
    __builtin_amdgcn_global_load_lds(
        (const __attribute__((address_space(1))) unsigned int*)g,
        (__attribute__((address_space(3))) unsigned int*)l, 16, 0, 0);
}

// ---------------------------------------------------------------------------
// Transpose + f32->bf16: featT[b][n][c] = feat[b][c][n]
// ---------------------------------------------------------------------------
__global__ __launch_bounds__(256) void conv_feat_k(const float* __restrict__ feat,
                                                   unsigned short* __restrict__ featT) {
    const int b = blockIdx.z;
    const int n0 = blockIdx.x * 64;
    const int c0 = blockIdx.y * 64;
    __shared__ float T[64][65];
    const int tid = threadIdx.x;
    const int r = tid >> 4, c4 = (tid & 15) * 4;
    const float* fb = feat + (size_t)b * DQ * NQ + (size_t)c0 * NQ + n0;
    for (int rr = 0; rr < 64; rr += 16) {
        float4 v = *(const float4*)(fb + (size_t)(rr + r) * NQ + c4);
        T[rr + r][c4 + 0] = v.x; T[rr + r][c4 + 1] = v.y;
        T[rr + r][c4 + 2] = v.z; T[rr + r][c4 + 3] = v.w;
    }
    __syncthreads();
    unsigned short* ob = featT + ((size_t)b * NQ + n0) * DQ + c0;
    for (int rr = 0; rr < 64; rr += 16) {
        int dr = rr + r;   // local n
        ushort4 w;
        w.x = f2bf(T[c4 + 0][dr]); w.y = f2bf(T[c4 + 1][dr]);
        w.z = f2bf(T[c4 + 2][dr]); w.w = f2bf(T[c4 + 3][dr]);
        *(ushort4*)(ob + (size_t)dr * DQ + c4) = w;
    }
}

// ---------------------------------------------------------------------------
// Transpose + f32->bf16 for both weights: WqT[j][c]=Wq[c][j], WoutT[d][j]=Wout[j][d]
// ---------------------------------------------------------------------------
__global__ __launch_bounds__(256) void conv_w_k(const float* __restrict__ Wq,
                                                const float* __restrict__ Wout,
                                                unsigned short* __restrict__ WqT,
                                                unsigned short* __restrict__ WoutT) {
    const float* src = blockIdx.z ? Wout : Wq;
    unsigned short* dst = blockIdx.z ? WoutT : WqT;
    const int r0 = blockIdx.x * 64;   // src row tile
    const int c0 = blockIdx.y * 64;   // src col tile
    __shared__ float T[64][65];
    const int tid = threadIdx.x;
    const int r = tid >> 4, c4 = (tid & 15) * 4;
    for (int rr = 0; rr < 64; rr += 16) {
        float4 v = *(const float4*)(src + (size_t)(r0 + rr + r) * DQ + c0 + c4);
        T[rr + r][c4 + 0] = v.x; T[rr + r][c4 + 1] = v.y;
        T[rr + r][c4 + 2] = v.z; T[rr + r][c4 + 3] = v.w;
    }
    __syncthreads();
    for (int rr = 0; rr < 64; rr += 16) {
        int dr = rr + r;
        ushort4 w;
        w.x = f2bf(T[c4 + 0][dr]); w.y = f2bf(T[c4 + 1][dr]);
        w.z = f2bf(T[c4 + 2][dr]); w.w = f2bf(T[c4 + 3][dr]);
        *(ushort4*)(dst + (size_t)(c0 + dr) * DQ + r0 + c4) = w;
    }
}

// ---------------------------------------------------------------------------
// kv = tokens @ Wkv  (f32, small: 1.2 GF)
// ---------------------------------------------------------------------------
__global__ __launch_bounds__(256) void gemm_kv_k(const float* __restrict__ tokens,
                                                 const float* __restrict__ Wkv,
                                                 float* __restrict__ kv_out) {
    const int b = blockIdx.z;
    const int j0 = blockIdx.x * 64;
    __shared__ float As[16][64];
    __shared__ float Bs[16][64];
    const int tid = threadIdx.x;
    const int tx = tid & 15, ty = tid >> 4;
    float acc[4][4] = {};
    const float* tb = tokens + (size_t)b * NT * DKV;
    for (int c0 = 0; c0 < DKV; c0 += 16) {
        {
            int m = tid >> 2, jq = tid & 3;
            float4 v = *(const float4*)(tb + (size_t)m * DKV + c0 + jq * 4);
            As[jq * 4 + 0][m] = v.x; As[jq * 4 + 1][m] = v.y;
            As[jq * 4 + 2][m] = v.z; As[jq * 4 + 3][m] = v.w;
            int kk = tid >> 4, n4 = (tid & 15) * 4;
            *(float4*)&Bs[kk][n4] = *(const float4*)(Wkv + (size_t)(c0 + kk) * (2 * DQ) + j0 + n4);
        }
        __syncthreads();
#pragma unroll
        for (int kk = 0; kk < 16; ++kk) {
            float a[4], bb[4];
            *(float4*)a  = *(float4*)&As[kk][ty * 4];
            *(float4*)bb = *(float4*)&Bs[kk][tx * 4];
#pragma unroll
            for (int i = 0; i < 4; ++i)
#pragma unroll
                for (int j = 0; j < 4; ++j)
                    acc[i][j] += a[i] * bb[j];
        }
        __syncthreads();
    }
    float* ob = kv_out + (size_t)b * NT * (2 * DQ);
#pragma unroll
    for (int i = 0; i < 4; ++i)
        *(float4*)(ob + (size_t)(ty * 4 + i) * (2 * DQ) + j0 + tx * 4) = *(float4*)acc[i];
}

// ---------------------------------------------------------------------------
// MFMA GEMM: q[b][n][j] = featT[b][n][:] . WqT[j][:]   (both bf16 K-contiguous)
// ---------------------------------------------------------------------------
__global__ __launch_bounds__(256) void gemm_q_mfma(const unsigned short* __restrict__ At,
                                                   const unsigned short* __restrict__ Bt,
                                                   unsigned short* __restrict__ C) {
    const int b = blockIdx.z;
    const int m0 = blockIdx.x * 128;
    const int n0 = blockIdx.y * 128;
    __shared__ __align__(16) unsigned short ldsA[128 * 32];
    __shared__ __align__(16) unsigned short ldsB[128 * 32];
    const int tid = threadIdx.x;
    const int lane = tid & 63;
    const int wm = ((tid >> 7) & 1) * 64;      // wave m offset
    const int wn = ((tid >> 6) & 1) * 64;      // wave n offset
    const int fr = lane & 15;
    const int fg = lane >> 4;
    const int pslot = (fg ^ ((fr >> 1) & 3)) * 16;   // physical 16B slot for frag reads
    const int wbase = (tid & 192) * 16;              // wave-uniform LDS byte base
    f32x4 acc[4][4] = {};

    const unsigned short* Ab = At + (size_t)b * NQ * DQ + (size_t)m0 * DQ;
    const unsigned short* Bb = Bt + (size_t)n0 * DQ;
    const int srow_lo = tid >> 2;
    const int sslot = tid & 3;

    for (int k0 = 0; k0 < DQ; k0 += 32) {
#pragma unroll
        for (int i = 0; i < 2; ++i) {
            int row = i * 64 + srow_lo;
            int sl = sslot ^ ((row >> 1) & 3);
            gload_lds16(Ab + (size_t)row * DQ + k0 + sl * 8,
                        (char*)ldsA + i * 4096 + wbase);
            gload_lds16(Bb + (size_t)row * DQ + k0 + sl * 8,
                        (char*)ldsB + i * 4096 + wbase);
        }
        __syncthreads();
        bf16x8 af[4], bfr[4];
#pragma unroll
        for (int f = 0; f < 4; ++f) {
            af[f]  = *(const bf16x8*)((const char*)ldsA + (wm + f * 16 + fr) * 64 + pslot);
            bfr[f] = *(const bf16x8*)((const char*)ldsB + (wn + f * 16 + fr) * 64 + pslot);
        }
#pragma unroll
        for (int i = 0; i < 4; ++i)
#pragma unroll
            for (int j = 0; j < 4; ++j)
                acc[i][j] = __builtin_amdgcn_mfma_f32_16x16x32_bf16(af[i], bfr[j], acc[i][j], 0, 0, 0);
        __syncthreads();
    }
    // C/D layout: col = lane&15, row = (lane>>4)*4 + reg   [m89/m91]
    unsigned short* Cb = C + (size_t)b * NQ * DQ;
#pragma unroll
    for (int i = 0; i < 4; ++i)
#pragma unroll
        for (int j = 0; j < 4; ++j) {
            int rbase = m0 + wm + i * 16 + fg * 4;
            int col = n0 + wn + j * 16 + fr;
#pragma unroll
            for (int r = 0; r < 4; ++r)
                Cb[(size_t)(rbase + r) * DQ + col] = f2bf(acc[i][j][r]);
        }
}

// ---------------------------------------------------------------------------
// MFMA GEMM (transposed output, fused residual+bias):
// out[b][d][n] = WoutT[d][:] . ao[b][n][:] + feat[b][d][n] + bout[d]
// ---------------------------------------------------------------------------
__global__ __launch_bounds__(256) void gemm_out_mfma(const unsigned short* __restrict__ At,
                                                     const unsigned short* __restrict__ Bt,
                                                     const float* __restrict__ feat,
                                                     const float* __restrict__ bout,
                                                     float* __restrict__ out) {
    const int b = blockIdx.z;
    const int m0 = blockIdx.x * 128;   // d
    const int n0 = blockIdx.y * 128;   // n
    __shared__ __align__(16) unsigned short ldsA[128 * 32];
    __shared__ __align__(16) unsigned short ldsB[128 * 32];
    const int tid = threadIdx.x;
    const int lane = tid & 63;
    const int wm = ((tid >> 7) & 1) * 64;
    const int wn = ((tid >> 6) & 1) * 64;
    const int fr = lane & 15;
    const int fg = lane >> 4;
    const int pslot = (fg ^ ((fr >> 1) & 3)) * 16;
    const int wbase = (tid & 192) * 16;
    f32x4 acc[4][4] = {};

    const unsigned short* Ab = At + (size_t)m0 * DQ;                          // WoutT (shared across b)
    const unsigned short* Bb = Bt + (size_t)b * NQ * DQ + (size_t)n0 * DQ;    // ao
    const int srow_lo = tid >> 2;
    const int sslot = tid & 3;

    for (int k0 = 0; k0 < DQ; k0 += 32) {
#pragma unroll
        for (int i = 0; i < 2; ++i) {
            int row = i * 64 + srow_lo;
            int sl = sslot ^ ((row >> 1) & 3);
            gload_lds16(Ab + (size_t)row * DQ + k0 + sl * 8,
                        (char*)ldsA + i * 4096 + wbase);
            gload_lds16(Bb + (size_t)row * DQ + k0 + sl * 8,
                        (char*)ldsB + i * 4096 + wbase);
        }
        __syncthreads();
        bf16x8 af[4], bfr[4];
#pragma unroll
        for (int f = 0; f < 4; ++f) {
            af[f]  = *(const bf16x8*)((const char*)ldsA + (wm + f * 16 + fr) * 64 + pslot);
            bfr[f] = *(const bf16x8*)((const char*)ldsB + (wn + f * 16 + fr) * 64 + pslot);
        }
#pragma unroll
        for (int i = 0; i < 4; ++i)
#pragma unroll
            for (int j = 0; j < 4; ++j)
                acc[i][j] = __builtin_amdgcn_mfma_f32_16x16x32_bf16(af[i], bfr[j], acc[i][j], 0, 0, 0);
        __syncthreads();
    }
    float* ob = out + (size_t)b * DQ * NQ;
    const float* fb = feat + (size_t)b * DQ * NQ;
#pragma unroll
    for (int i = 0; i < 4; ++i)
#pragma unroll
        for (int j = 0; j < 4; ++j) {
            int dbase = m0 + wm + i * 16 + fg * 4;
            int n = n0 + wn + j * 16 + fr;
#pragma unroll
            for (int r = 0; r < 4; ++r) {
                int d = dbase + r;
                size_t idx = (size_t)d * NQ + n;
                ob[idx] = acc[i][j][r] + fb[idx] + bout[d];
            }
        }
}

// ---------------------------------------------------------------------------
// MFMA attention per (b, h, 256 q-rows). K staged with fused RoPE (bf16),
// V staged transposed (bf16); both held as register fragments per wave.
// Q frags loaded straight from global (A-frag is hd-contiguous), RoPE'd
// in-register with 1/8 scale folded in. P and out tiles bounce through a
// wave-private LDS tile (in-order per-wave LDS => no barriers in main loop).
// Writes ao (bf16) IN PLACE over q.
// ---------------------------------------------------------------------------
__global__ __launch_bounds__(256) void attn_mfma(const float* __restrict__ kv,
                                                 unsigned short* __restrict__ q) {
    const int qb = blockIdx.x, h = blockIdx.y, b = blockIdx.z;
    const int n0 = qb * 256;
    __shared__ __align__(16) unsigned short Ks[64][72];   // RoPE'd K, [t][d]
    __shared__ __align__(16) unsigned short VT[64][72];   // V^T, [d][t]
    __shared__ __align__(16) unsigned short Ps[4][16][72];// per-wave P/out bounce
    const int tid = threadIdx.x;
    const int lane = tid & 63;
    const int wid = tid >> 6;
    const int fr = lane & 15;   // frag row/col index
    const int fg = lane >> 4;   // frag k-group

    // ---- stage K with RoPE ----
    {
        const int t = tid >> 2, dg = (tid & 3) * 8;
        const float* krow = kv + ((size_t)b * NT + t) * (2 * DQ) + h * HD;
        float lo[8], hi[8];
        *(float4*)&lo[0] = *(const float4*)(krow + dg);
        *(float4*)&lo[4] = *(const float4*)(krow + dg + 4);
        *(float4*)&hi[0] = *(const float4*)(krow + dg + 32);
        *(float4*)&hi[4] = *(const float4*)(krow + dg + 36);
        union { bf16x8 v; unsigned short u[8]; } plo, phi;
#pragma unroll
        for (int e = 0; e < 8; ++e) {
            float inv = exp2f((float)(dg + e) * -0.41524101186092029f);  // -log2(1e4)/32
            float s, c; __sincosf((float)t * inv, &s, &c);
            plo.u[e] = f2bf(lo[e] * c - hi[e] * s);
            phi.u[e] = f2bf(hi[e] * c + lo[e] * s);
        }
        *(bf16x8*)&Ks[t][dg]      = plo.v;
        *(bf16x8*)&Ks[t][dg + 32] = phi.v;
    }
    // ---- stage V transposed ----
    {
        const int t = tid >> 2, d0 = (tid & 3) * 16;
        const float* vrow = kv + ((size_t)b * NT + t) * (2 * DQ) + DQ + h * HD + d0;
        float vv[16];
        *(float4*)&vv[0]  = *(const float4*)(vrow + 0);
        *(float4*)&vv[4]  = *(const float4*)(vrow + 4);
        *(float4*)&vv[8]  = *(const float4*)(vrow + 8);
        *(float4*)&vv[12] = *(const float4*)(vrow + 12);
#pragma unroll
        for (int dd = 0; dd < 16; ++dd)
            VT[d0 + dd][t] = f2bf(vv[dd]);
    }
    __syncthreads();

    // ---- K, V fragments to registers (held for whole kernel) ----
    bf16x8 kf[4][2], vf[4][2];
#pragma unroll
    for (int j = 0; j < 4; ++j)
#pragma unroll
        for (int hh = 0; hh < 2; ++hh) {
            kf[j][hh] = *(const bf16x8*)&Ks[j * 16 + fr][hh * 32 + fg * 8];
            vf[j][hh] = *(const bf16x8*)&VT[j * 16 + fr][hh * 32 + fg * 8];
        }

    // per-lane RoPE inv-freqs for q frag elements (d = fg*8+e, d<32 half)
    float invf[8];
#pragma unroll
    for (int e = 0; e < 8; ++e)
        invf[e] = exp2f((float)(fg * 8 + e) * -0.41524101186092029f);

    unsigned short* qbase = q + ((size_t)b * NQ + n0) * DQ + h * HD;

    for (int rt = wid; rt < 16; rt += 4) {
        const int row = rt * 16 + fr;
        const unsigned short* qrow = qbase + (size_t)row * DQ + fg * 8;
        bf16x8 q0 = *(const bf16x8*)qrow;          // d = fg*8..+8
        bf16x8 q1 = *(const bf16x8*)(qrow + 32);   // d+32
        union { bf16x8 v; unsigned short u[8]; } qa, qb2;
        const float pos = (float)(n0 + row);
#pragma unroll
        for (int e = 0; e < 8; ++e) {
            float s, c; __sincosf(pos * invf[e], &s, &c);
            float v0 = bf2f((unsigned short)q0[e]);
            float v1 = bf2f((unsigned short)q1[e]);
            qa.u[e]  = f2bf((v0 * c - v1 * s) * 0.125f);   // fold hd^-0.5
            qb2.u[e] = f2bf((v1 * c + v0 * s) * 0.125f);
        }
        // S = Q K^T : 4 col-tiles x 2 k-halves
        f32x4 sc[4];
#pragma unroll
        for (int j = 0; j < 4; ++j) {
            f32x4 z = {};
            sc[j] = __builtin_amdgcn_mfma_f32_16x16x32_bf16(qa.v, kf[j][0], z, 0, 0, 0);
            sc[j] = __builtin_amdgcn_mfma_f32_16x16x32_bf16(qb2.v, kf[j][1], sc[j], 0, 0, 0);
        }
        // softmax over t: lane holds S[q=(fg*4+r)][t=j*16+fr]; reduce over fr
#pragma unroll
        for (int r = 0; r < 4; ++r) {
            float m = fmaxf(fmaxf(sc[0][r], sc[1][r]), fmaxf(sc[2][r], sc[3][r]));
            for (int off = 1; off < 16; off <<= 1) m = fmaxf(m, __shfl_xor(m, off));
            float s = 0.f;
#pragma unroll
            for (int j = 0; j < 4; ++j) { float p = __expf(sc[j][r] - m); sc[j][r] = p; s += p; }
            for (int off = 1; off < 16; off <<= 1) s += __shfl_xor(s, off);
            float is = 1.0f / s;
#pragma unroll
            for (int j = 0; j < 4; ++j) sc[j][r] *= is;
        }
        // P scatter (D-layout) -> LDS -> reload as A-frags
#pragma unroll
        for (int r = 0; r < 4; ++r)
#pragma unroll
            for (int j = 0; j < 4; ++j)
                Ps[wid][fg * 4 + r][j * 16 + fr] = f2bf(sc[j][r]);
        bf16x8 pa0 = *(const bf16x8*)&Ps[wid][fr][fg * 8];
        bf16x8 pa1 = *(const bf16x8*)&Ps[wid][fr][32 + fg * 8];
        // out = P V : 4 d-tiles x 2 t-halves; scatter result into same LDS tile
#pragma unroll
        for (int n = 0; n < 4; ++n) {
            f32x4 z = {};
            f32x4 o = __builtin_amdgcn_mfma_f32_16x16x32_bf16(pa0, vf[n][0], z, 0, 0, 0);
            o = __builtin_amdgcn_mfma_f32_16x16x32_bf16(pa1, vf[n][1], o, 0, 0, 0);
#pragma unroll
            for (int r = 0; r < 4; ++r)
                Ps[wid][fg * 4 + r][n * 16 + fr] = f2bf(o[r]);
        }
        // coalesced writeback (in place over q)
#pragma unroll
        for (int p = 0; p < 2; ++p) {
            int rr = p * 8 + (lane >> 3), ch = lane & 7;
            bf16x8 ov = *(const bf16x8*)&Ps[wid][rr][ch * 8];
            *(bf16x8*)(qbase + (size_t)(rt * 16 + rr) * DQ + ch * 8) = ov;
        }
    }
}

// ---------------------------------------------------------------------------
extern "C" void kernel_launch(void* const* d_in, const int* in_sizes, int n_in,
                              void* d_out, int out_size, void* d_ws, size_t ws_size,
                              hipStream_t stream) {
    const float* feat   = (const float*)d_in[0];
    const float* tokens = (const float*)d_in[1];
    const float* Wq     = (const float*)d_in[2];
    const float* Wkv    = (const float*)d_in[3];
    const float* Wout   = (const float*)d_in[4];
    const float* bout   = (const float*)d_in[5];
    float* out = (float*)d_out;

    float* ws_kv = (float*)d_ws;                                        // [B][NT][2*DQ] f32
    unsigned short* ws_featT = (unsigned short*)(ws_kv + (size_t)BATCH * NT * 2 * DQ);  // [B][NQ][DQ] bf16
    unsigned short* ws_q     = ws_featT + (size_t)BATCH * NQ * DQ;      // [B][NQ][DQ] bf16 (q, then ao in place)
    unsigned short* ws_WqT   = ws_q + (size_t)BATCH * NQ * DQ;          // [DQ][DQ] bf16
    unsigned short* ws_WoutT = ws_WqT + (size_t)DQ * DQ;                // [DQ][DQ] bf16

    conv_w_k<<<dim3(12, 12, 2), 256, 0, stream>>>(Wq, Wout, ws_WqT, ws_WoutT);
    conv_feat_k<<<dim3(16, 12, BATCH), 256, 0, stream>>>(feat, ws_featT);
    gemm_kv_k<<<dim3(24, 1, BATCH), 256, 0, stream>>>(tokens, Wkv, ws_kv);
    gemm_q_mfma<<<dim3(8, 6, BATCH), 256, 0, stream>>>(ws_featT, ws_WqT, ws_q);
    attn_mfma<<<dim3(4, 12, BATCH), 256, 0, stream>>>(ws_kv, ws_q);
    gemm_out_mfma<<<dim3(6, 8, BATCH), 256, 0, stream>>>(ws_WoutT, ws_q, feat, bout, out);
}

// Round 7
// 229.952 us; speedup vs baseline: 3.2194x; 1.0024x over previous
//
#include <hip/hip_runtime.h>
#include <stdint.h>

#define BATCH 16
#define DQ 768
#define NQ 1024      // T*Hp*Wp
#define NT 64
#define DKV 384
#define NHEAD 12
#define HD 64
#define HD2 32

typedef __attribute__((ext_vector_type(8))) short bf16x8;
typedef __attribute__((ext_vector_type(4))) float f32x4;

__device__ __forceinline__ unsigned short f2bf(float f) {
    unsigned u = __float_as_uint(f);
    u += 0x7fff + ((u >> 16) & 1);          // RNE (inputs finite)
    return (unsigned short)(u >> 16);
}
__device__ __forceinline__ float bf2f(unsigned short h) {
    return __uint_as_float((unsigned)h << 16);
}

__device__ __forceinline__ void gload_lds16(const void* g, void* l) {
    __builtin_amdgcn_global_load_lds(
        (const __attribute__((address_space(1))) unsigned int*)g,
        (__attribute__((address_space(3))) unsigned int*)l, 16, 0, 0);
}

// ---------------------------------------------------------------------------
// Transpose + f32->bf16: featT[b][n][c] = feat[b][c][n]
// ---------------------------------------------------------------------------
__global__ __launch_bounds__(256) void conv_feat_k(const float* __restrict__ feat,
                                                   unsigned short* __restrict__ featT) {
    const int b = blockIdx.z;
    const int n0 = blockIdx.x * 64;
    const int c0 = blockIdx.y * 64;
    __shared__ float T[64][65];
    const int tid = threadIdx.x;
    const int r = tid >> 4, c4 = (tid & 15) * 4;
    const float* fb = feat + (size_t)b * DQ * NQ + (size_t)c0 * NQ + n0;
    for (int rr = 0; rr < 64; rr += 16) {
        float4 v = *(const float4*)(fb + (size_t)(rr + r) * NQ + c4);
        T[rr + r][c4 + 0] = v.x; T[rr + r][c4 + 1] = v.y;
        T[rr + r][c4 + 2] = v.z; T[rr + r][c4 + 3] = v.w;
    }
    __syncthreads();
    unsigned short* ob = featT + ((size_t)b * NQ + n0) * DQ + c0;
    for (int rr = 0; rr < 64; rr += 16) {
        int dr = rr + r;   // local n
        ushort4 w;
        w.x = f2bf(T[c4 + 0][dr]); w.y = f2bf(T[c4 + 1][dr]);
        w.z = f2bf(T[c4 + 2][dr]); w.w = f2bf(T[c4 + 3][dr]);
        *(ushort4*)(ob + (size_t)dr * DQ + c4) = w;
    }
}

// ---------------------------------------------------------------------------
// Transpose + f32->bf16 for both weights: WqT[j][c]=Wq[c][j], WoutT[d][j]=Wout[j][d]
// ---------------------------------------------------------------------------
__global__ __launch_bounds__(256) void conv_w_k(const float* __restrict__ Wq,
                                                const float* __restrict__ Wout,
                                                unsigned short* __restrict__ WqT,
                                                unsigned short* __restrict__ WoutT) {
    const float* src = blockIdx.z ? Wout : Wq;
    unsigned short* dst = blockIdx.z ? WoutT : WqT;
    const int r0 = blockIdx.x * 64;   // src row tile
    const int c0 = blockIdx.y * 64;   // src col tile
    __shared__ float T[64][65];
    const int tid = threadIdx.x;
    const int r = tid >> 4, c4 = (tid & 15) * 4;
    for (int rr = 0; rr < 64; rr += 16) {
        float4 v = *(const float4*)(src + (size_t)(r0 + rr + r) * DQ + c0 + c4);
        T[rr + r][c4 + 0] = v.x; T[rr + r][c4 + 1] = v.y;
        T[rr + r][c4 + 2] = v.z; T[rr + r][c4 + 3] = v.w;
    }
    __syncthreads();
    for (int rr = 0; rr < 64; rr += 16) {
        int dr = rr + r;
        ushort4 w;
        w.x = f2bf(T[c4 + 0][dr]); w.y = f2bf(T[c4 + 1][dr]);
        w.z = f2bf(T[c4 + 2][dr]); w.w = f2bf(T[c4 + 3][dr]);
        *(ushort4*)(dst + (size_t)(c0 + dr) * DQ + r0 + c4) = w;
    }
}

// ---------------------------------------------------------------------------
// kv = tokens @ Wkv  (f32, small: 1.2 GF)
// ---------------------------------------------------------------------------
__global__ __launch_bounds__(256) void gemm_kv_k(const float* __restrict__ tokens,
                                                 const float* __restrict__ Wkv,
                                                 float* __restrict__ kv_out) {
    const int b = blockIdx.z;
    const int j0 = blockIdx.x * 64;
    __shared__ float As[16][64];
    __shared__ float Bs[16][64];
    const int tid = threadIdx.x;
    const int tx = tid & 15, ty = tid >> 4;
    float acc[4][4] = {};
    const float* tb = tokens + (size_t)b * NT * DKV;
    for (int c0 = 0; c0 < DKV; c0 += 16) {
        {
            int m = tid >> 2, jq = tid & 3;
            float4 v = *(const float4*)(tb + (size_t)m * DKV + c0 + jq * 4);
            As[jq * 4 + 0][m] = v.x; As[jq * 4 + 1][m] = v.y;
            As[jq * 4 + 2][m] = v.z; As[jq * 4 + 3][m] = v.w;
            int kk = tid >> 4, n4 = (tid & 15) * 4;
            *(float4*)&Bs[kk][n4] = *(const float4*)(Wkv + (size_t)(c0 + kk) * (2 * DQ) + j0 + n4);
        }
        __syncthreads();
#pragma unroll
        for (int kk = 0; kk < 16; ++kk) {
            float a[4], bb[4];
            *(float4*)a  = *(float4*)&As[kk][ty * 4];
            *(float4*)bb = *(float4*)&Bs[kk][tx * 4];
#pragma unroll
            for (int i = 0; i < 4; ++i)
#pragma unroll
                for (int j = 0; j < 4; ++j)
                    acc[i][j] += a[i] * bb[j];
        }
        __syncthreads();
    }
    float* ob = kv_out + (size_t)b * NT * (2 * DQ);
#pragma unroll
    for (int i = 0; i < 4; ++i)
        *(float4*)(ob + (size_t)(ty * 4 + i) * (2 * DQ) + j0 + tx * 4) = *(float4*)acc[i];
}

// ---------------------------------------------------------------------------
// MFMA GEMM, 2-phase double-buffered (T3-min): issue next-tile
// global_load_lds BEFORE computing current tile so the barrier's vmcnt
// drain lands after the MFMAs (staging latency hidden under compute).
// q[b][n][j] = featT[b][n][:] . WqT[j][:]
// ---------------------------------------------------------------------------
__global__ __launch_bounds__(256) void gemm_q_mfma(const unsigned short* __restrict__ At,
                                                   const unsigned short* __restrict__ Bt,
                                                   unsigned short* __restrict__ C) {
    const int b = blockIdx.z;
    const int m0 = blockIdx.x * 128;
    const int n0 = blockIdx.y * 128;
    __shared__ __align__(16) unsigned short ldsA[2][128 * 32];
    __shared__ __align__(16) unsigned short ldsB[2][128 * 32];
    const int tid = threadIdx.x;
    const int lane = tid & 63;
    const int wm = ((tid >> 7) & 1) * 64;      // wave m offset
    const int wn = ((tid >> 6) & 1) * 64;      // wave n offset
    const int fr = lane & 15;
    const int fg = lane >> 4;
    const int pslot = (fg ^ ((fr >> 1) & 3)) * 16;   // physical 16B slot for frag reads
    const int wbase = (tid & 192) * 16;              // wave-uniform LDS byte base
    f32x4 acc[4][4] = {};

    const unsigned short* Ab = At + (size_t)b * NQ * DQ + (size_t)m0 * DQ;
    const unsigned short* Bb = Bt + (size_t)n0 * DQ;
    const int srow_lo = tid >> 2;
    const int sslot = tid & 3;

    auto STAGE = [&](int buf, int k0) {
#pragma unroll
        for (int i = 0; i < 2; ++i) {
            int row = i * 64 + srow_lo;
            int sl = sslot ^ ((row >> 1) & 3);
            gload_lds16(Ab + (size_t)row * DQ + k0 + sl * 8,
                        (char*)ldsA[buf] + i * 4096 + wbase);
            gload_lds16(Bb + (size_t)row * DQ + k0 + sl * 8,
                        (char*)ldsB[buf] + i * 4096 + wbase);
        }
    };

    STAGE(0, 0);
    __syncthreads();
    int cur = 0;
    const int NSTEP = DQ / 32;   // 24
    for (int t = 0; t < NSTEP; ++t) {
        if (t + 1 < NSTEP) STAGE(cur ^ 1, (t + 1) * 32);   // issue-early prefetch
        bf16x8 af[4], bfr[4];
#pragma unroll
        for (int f = 0; f < 4; ++f) {
            af[f]  = *(const bf16x8*)((const char*)ldsA[cur] + (wm + f * 16 + fr) * 64 + pslot);
            bfr[f] = *(const bf16x8*)((const char*)ldsB[cur] + (wn + f * 16 + fr) * 64 + pslot);
        }
#pragma unroll
        for (int i = 0; i < 4; ++i)
#pragma unroll
            for (int j = 0; j < 4; ++j)
                acc[i][j] = __builtin_amdgcn_mfma_f32_16x16x32_bf16(af[i], bfr[j], acc[i][j], 0, 0, 0);
        __syncthreads();   // drains next-tile loads AFTER this tile's MFMAs
        cur ^= 1;
    }
    // C/D layout: col = lane&15, row = (lane>>4)*4 + reg   [m89/m91]
    unsigned short* Cb = C + (size_t)b * NQ * DQ;
#pragma unroll
    for (int i = 0; i < 4; ++i)
#pragma unroll
        for (int j = 0; j < 4; ++j) {
            int rbase = m0 + wm + i * 16 + fg * 4;
            int col = n0 + wn + j * 16 + fr;
#pragma unroll
            for (int r = 0; r < 4; ++r)
                Cb[(size_t)(rbase + r) * DQ + col] = f2bf(acc[i][j][r]);
        }
}

// ---------------------------------------------------------------------------
// MFMA GEMM (transposed output, fused residual+bias), 2-phase dbuf:
// out[b][d][n] = WoutT[d][:] . ao[b][n][:] + feat[b][d][n] + bout[d]
// ---------------------------------------------------------------------------
__global__ __launch_bounds__(256) void gemm_out_mfma(const unsigned short* __restrict__ At,
                                                     const unsigned short* __restrict__ Bt,
                                                     const float* __restrict__ feat,
                                                     const float* __restrict__ bout,
                                                     float* __restrict__ out) {
    const int b = blockIdx.z;
    const int m0 = blockIdx.x * 128;   // d
    const int n0 = blockIdx.y * 128;   // n
    __shared__ __align__(16) unsigned short ldsA[2][128 * 32];
    __shared__ __align__(16) unsigned short ldsB[2][128 * 32];
    const int tid = threadIdx.x;
    const int lane = tid & 63;
    const int wm = ((tid >> 7) & 1) * 64;
    const int wn = ((tid >> 6) & 1) * 64;
    const int fr = lane & 15;
    const int fg = lane >> 4;
    const int pslot = (fg ^ ((fr >> 1) & 3)) * 16;
    const int wbase = (tid & 192) * 16;
    f32x4 acc[4][4] = {};

    const unsigned short* Ab = At + (size_t)m0 * DQ;                          // WoutT (shared across b)
    const unsigned short* Bb = Bt + (size_t)b * NQ * DQ + (size_t)n0 * DQ;    // ao
    const int srow_lo = tid >> 2;
    const int sslot = tid & 3;

    auto STAGE = [&](int buf, int k0) {
#pragma unroll
        for (int i = 0; i < 2; ++i) {
            int row = i * 64 + srow_lo;
            int sl = sslot ^ ((row >> 1) & 3);
            gload_lds16(Ab + (size_t)row * DQ + k0 + sl * 8,
                        (char*)ldsA[buf] + i * 4096 + wbase);
            gload_lds16(Bb + (size_t)row * DQ + k0 + sl * 8,
                        (char*)ldsB[buf] + i * 4096 + wbase);
        }
    };

    STAGE(0, 0);
    __syncthreads();
    int cur = 0;
    const int NSTEP = DQ / 32;   // 24
    for (int t = 0; t < NSTEP; ++t) {
        if (t + 1 < NSTEP) STAGE(cur ^ 1, (t + 1) * 32);
        bf16x8 af[4], bfr[4];
#pragma unroll
        for (int f = 0; f < 4; ++f) {
            af[f]  = *(const bf16x8*)((const char*)ldsA[cur] + (wm + f * 16 + fr) * 64 + pslot);
            bfr[f] = *(const bf16x8*)((const char*)ldsB[cur] + (wn + f * 16 + fr) * 64 + pslot);
        }
#pragma unroll
        for (int i = 0; i < 4; ++i)
#pragma unroll
            for (int j = 0; j < 4; ++j)
                acc[i][j] = __builtin_amdgcn_mfma_f32_16x16x32_bf16(af[i], bfr[j], acc[i][j], 0, 0, 0);
        __syncthreads();
        cur ^= 1;
    }
    float* ob = out + (size_t)b * DQ * NQ;
    const float* fb = feat + (size_t)b * DQ * NQ;
#pragma unroll
    for (int i = 0; i < 4; ++i)
#pragma unroll
        for (int j = 0; j < 4; ++j) {
            int dbase = m0 + wm + i * 16 + fg * 4;
            int n = n0 + wn + j * 16 + fr;
#pragma unroll
            for (int r = 0; r < 4; ++r) {
                int d = dbase + r;
                size_t idx = (size_t)d * NQ + n;
                ob[idx] = acc[i][j][r] + fb[idx] + bout[d];
            }
        }
}

// ---------------------------------------------------------------------------
// MFMA attention per (b, h, 256 q-rows). K staged with fused RoPE (bf16),
// V staged transposed (bf16); both held as register fragments per wave.
// Q frags loaded straight from global, RoPE'd in-register with 1/8 scale
// folded in. P/out bounce through a wave-private LDS tile (no barriers in
// main loop). Writes ao (bf16) IN PLACE over q.
// ---------------------------------------------------------------------------
__global__ __launch_bounds__(256) void attn_mfma(const float* __restrict__ kv,
                                                 unsigned short* __restrict__ q) {
    const int qb = blockIdx.x, h = blockIdx.y, b = blockIdx.z;
    const int n0 = qb * 256;
    __shared__ __align__(16) unsigned short Ks[64][72];   // RoPE'd K, [t][d]
    __shared__ __align__(16) unsigned short VT[64][72];   // V^T, [d][t]
    __shared__ __align__(16) unsigned short Ps[4][16][72];// per-wave P/out bounce
    const int tid = threadIdx.x;
    const int lane = tid & 63;
    const int wid = tid >> 6;
    const int fr = lane & 15;   // frag row/col index
    const int fg = lane >> 4;   // frag k-group

    // ---- stage K with RoPE ----
    {
        const int t = tid >> 2, dg = (tid & 3) * 8;
        const float* krow = kv + ((size_t)b * NT + t) * (2 * DQ) + h * HD;
        float lo[8], hi[8];
        *(float4*)&lo[0] = *(const float4*)(krow + dg);
        *(float4*)&lo[4] = *(const float4*)(krow + dg + 4);
        *(float4*)&hi[0] = *(const float4*)(krow + dg + 32);
        *(float4*)&hi[4] = *(const float4*)(krow + dg + 36);
        union { bf16x8 v; unsigned short u[8]; } plo, phi;
#pragma unroll
        for (int e = 0; e < 8; ++e) {
            float inv = exp2f((float)(dg + e) * -0.41524101186092029f);  // -log2(1e4)/32
            float s, c; __sincosf((float)t * inv, &s, &c);
            plo.u[e] = f2bf(lo[e] * c - hi[e] * s);
            phi.u[e] = f2bf(hi[e] * c + lo[e] * s);
        }
        *(bf16x8*)&Ks[t][dg]      = plo.v;
        *(bf16x8*)&Ks[t][dg + 32] = phi.v;
    }
    // ---- stage V transposed ----
    {
        const int t = tid >> 2, d0 = (tid & 3) * 16;
        const float* vrow = kv + ((size_t)b * NT + t) * (2 * DQ) + DQ + h * HD + d0;
        float vv[16];
        *(float4*)&vv[0]  = *(const float4*)(vrow + 0);
        *(float4*)&vv[4]  = *(const float4*)(vrow + 4);
        *(float4*)&vv[8]  = *(const float4*)(vrow + 8);
        *(float4*)&vv[12] = *(const float4*)(vrow + 12);
#pragma unroll
        for (int dd = 0; dd < 16; ++dd)
            VT[d0 + dd][t] = f2bf(vv[dd]);
    }
    __syncthreads();

    // ---- K, V fragments to registers (held for whole kernel) ----
    bf16x8 kf[4][2], vf[4][2];
#pragma unroll
    for (int j = 0; j < 4; ++j)
#pragma unroll
        for (int hh = 0; hh < 2; ++hh) {
            kf[j][hh] = *(const bf16x8*)&Ks[j * 16 + fr][hh * 32 + fg * 8];
            vf[j][hh] = *(const bf16x8*)&VT[j * 16 + fr][hh * 32 + fg * 8];
        }

    // per-lane RoPE inv-freqs for q frag elements (d = fg*8+e, d<32 half)
    float invf[8];
#pragma unroll
    for (int e = 0; e < 8; ++e)
        invf[e] = exp2f((float)(fg * 8 + e) * -0.41524101186092029f);

    unsigned short* qbase = q + ((size_t)b * NQ + n0) * DQ + h * HD;

    for (int rt = wid; rt < 16; rt += 4) {
        const int row = rt * 16 + fr;
        const unsigned short* qrow = qbase + (size_t)row * DQ + fg * 8;
        bf16x8 q0 = *(const bf16x8*)qrow;          // d = fg*8..+8
        bf16x8 q1 = *(const bf16x8*)(qrow + 32);   // d+32
        union { bf16x8 v; unsigned short u[8]; } qa, qb2;
        const float pos = (float)(n0 + row);
#pragma unroll
        for (int e = 0; e < 8; ++e) {
            float s, c; __sincosf(pos * invf[e], &s, &c);
            float v0 = bf2f((unsigned short)q0[e]);
            float v1 = bf2f((unsigned short)q1[e]);
            qa.u[e]  = f2bf((v0 * c - v1 * s) * 0.125f);   // fold hd^-0.5
            qb2.u[e] = f2bf((v1 * c + v0 * s) * 0.125f);
        }
        // S = Q K^T : 4 col-tiles x 2 k-halves
        f32x4 sc[4];
#pragma unroll
        for (int j = 0; j < 4; ++j) {
            f32x4 z = {};
            sc[j] = __builtin_amdgcn_mfma_f32_16x16x32_bf16(qa.v, kf[j][0], z, 0, 0, 0);
            sc[j] = __builtin_amdgcn_mfma_f32_16x16x32_bf16(qb2.v, kf[j][1], sc[j], 0, 0, 0);
        }
        // softmax over t: lane holds S[q=(fg*4+r)][t=j*16+fr]; reduce over fr
#pragma unroll
        for (int r = 0; r < 4; ++r) {
            float m = fmaxf(fmaxf(sc[0][r], sc[1][r]), fmaxf(sc[2][r], sc[3][r]));
            for (int off = 1; off < 16; off <<= 1) m = fmaxf(m, __shfl_xor(m, off));
            float s = 0.f;
#pragma unroll
            for (int j = 0; j < 4; ++j) { float p = __expf(sc[j][r] - m); sc[j][r] = p; s += p; }
            for (int off = 1; off < 16; off <<= 1) s += __shfl_xor(s, off);
            float is = 1.0f / s;
#pragma unroll
            for (int j = 0; j < 4; ++j) sc[j][r] *= is;
        }
        // P scatter (D-layout) -> LDS -> reload as A-frags
#pragma unroll
        for (int r = 0; r < 4; ++r)
#pragma unroll
            for (int j = 0; j < 4; ++j)
                Ps[wid][fg * 4 + r][j * 16 + fr] = f2bf(sc[j][r]);
        bf16x8 pa0 = *(const bf16x8*)&Ps[wid][fr][fg * 8];
        bf16x8 pa1 = *(const bf16x8*)&Ps[wid][fr][32 + fg * 8];
        // out = P V : 4 d-tiles x 2 t-halves; scatter result into same LDS tile
#pragma unroll
        for (int n = 0; n < 4; ++n) {
            f32x4 z = {};
            f32x4 o = __builtin_amdgcn_mfma_f32_16x16x32_bf16(pa0, vf[n][0], z, 0, 0, 0);
            o = __builtin_amdgcn_mfma_f32_16x16x32_bf16(pa1, vf[n][1], o, 0, 0, 0);
#pragma unroll
            for (int r = 0; r < 4; ++r)
                Ps[wid][fg * 4 + r][n * 16 + fr] = f2bf(o[r]);
        }
        // coalesced writeback (in place over q)
#pragma unroll
        for (int p = 0; p < 2; ++p) {
            int rr = p * 8 + (lane >> 3), ch = lane & 7;
            bf16x8 ov = *(const bf16x8*)&Ps[wid][rr][ch * 8];
            *(bf16x8*)(qbase + (size_t)(rt * 16 + rr) * DQ + ch * 8) = ov;
        }
    }
}

// ---------------------------------------------------------------------------
extern "C" void kernel_launch(void* const* d_in, const int* in_sizes, int n_in,
                              void* d_out, int out_size, void* d_ws, size_t ws_size,
                              hipStream_t stream) {
    const float* feat   = (const float*)d_in[0];
    const float* tokens = (const float*)d_in[1];
    const float* Wq     = (const float*)d_in[2];
    const float* Wkv    = (const float*)d_in[3];
    const float* Wout   = (const float*)d_in[4];
    const float* bout   = (const float*)d_in[5];
    float* out = (float*)d_out;

    float* ws_kv = (float*)d_ws;                                        // [B][NT][2*DQ] f32
    unsigned short* ws_featT = (unsigned short*)(ws_kv + (size_t)BATCH * NT * 2 * DQ);  // [B][NQ][DQ] bf16
    unsigned short* ws_q     = ws_featT + (size_t)BATCH * NQ * DQ;      // [B][NQ][DQ] bf16 (q, then ao in place)
    unsigned short* ws_WqT   = ws_q + (size_t)BATCH * NQ * DQ;          // [DQ][DQ] bf16
    unsigned short* ws_WoutT = ws_WqT + (size_t)DQ * DQ;                // [DQ][DQ] bf16

    conv_w_k<<<dim3(12, 12, 2), 256, 0, stream>>>(Wq, Wout, ws_WqT, ws_WoutT);
    conv_feat_k<<<dim3(16, 12, BATCH), 256, 0, stream>>>(feat, ws_featT);
    gemm_kv_k<<<dim3(24, 1, BATCH), 256, 0, stream>>>(tokens, Wkv, ws_kv);
    gemm_q_mfma<<<dim3(8, 6, BATCH), 256, 0, stream>>>(ws_featT, ws_WqT, ws_q);
    attn_mfma<<<dim3(4, 12, BATCH), 256, 0, stream>>>(ws_kv, ws_q);
    gemm_out_mfma<<<dim3(6, 8, BATCH), 256, 0, stream>>>(ws_WoutT, ws_q, feat, bout, out);
}

// Round 8
// 222.763 us; speedup vs baseline: 3.3233x; 1.0323x over previous
//
#include <hip/hip_runtime.h>
#include <stdint.h>

#define BATCH 16
#define DQ 768
#define NQ 1024      // T*Hp*Wp
#define NT 64
#define DKV 384
#define NHEAD 12
#define HD 64
#define HD2 32

typedef __attribute__((ext_vector_type(8))) short bf16x8;
typedef __attribute__((ext_vector_type(4))) float f32x4;

__device__ __forceinline__ unsigned short f2bf(float f) {
    unsigned u = __float_as_uint(f);
    u += 0x7fff + ((u >> 16) & 1);          // RNE (inputs finite)
    return (unsigned short)(u >> 16);
}
__device__ __forceinline__ float bf2f(unsigned short h) {
    return __uint_as_float((unsigned)h << 16);
}

__device__ __forceinline__ void gload_lds16(const void* g, void* l) {
    __builtin_amdgcn_global_load_lds(
        (const __attribute__((address_space(1))) unsigned int*)g,
        (__attribute__((address_space(3))) unsigned int*)l, 16, 0, 0);
}

// ---------------------------------------------------------------------------
// Transpose + f32->bf16: featT[b][n][c] = feat[b][c][n]
// ---------------------------------------------------------------------------
__global__ __launch_bounds__(256) void conv_feat_k(const float* __restrict__ feat,
                                                   unsigned short* __restrict__ featT) {
    const int b = blockIdx.z;
    const int n0 = blockIdx.x * 64;
    const int c0 = blockIdx.y * 64;
    __shared__ float T[64][65];
    const int tid = threadIdx.x;
    const int r = tid >> 4, c4 = (tid & 15) * 4;
    const float* fb = feat + (size_t)b * DQ * NQ + (size_t)c0 * NQ + n0;
    for (int rr = 0; rr < 64; rr += 16) {
        float4 v = *(const float4*)(fb + (size_t)(rr + r) * NQ + c4);
        T[rr + r][c4 + 0] = v.x; T[rr + r][c4 + 1] = v.y;
        T[rr + r][c4 + 2] = v.z; T[rr + r][c4 + 3] = v.w;
    }
    __syncthreads();
    unsigned short* ob = featT + ((size_t)b * NQ + n0) * DQ + c0;
    for (int rr = 0; rr < 64; rr += 16) {
        int dr = rr + r;   // local n
        ushort4 w;
        w.x = f2bf(T[c4 + 0][dr]); w.y = f2bf(T[c4 + 1][dr]);
        w.z = f2bf(T[c4 + 2][dr]); w.w = f2bf(T[c4 + 3][dr]);
        *(ushort4*)(ob + (size_t)dr * DQ + c4) = w;
    }
}

// ---------------------------------------------------------------------------
// Transpose + f32->bf16 for both weights: WqT[j][c]=Wq[c][j], WoutT[d][j]=Wout[j][d]
// ---------------------------------------------------------------------------
__global__ __launch_bounds__(256) void conv_w_k(const float* __restrict__ Wq,
                                                const float* __restrict__ Wout,
                                                unsigned short* __restrict__ WqT,
                                                unsigned short* __restrict__ WoutT) {
    const float* src = blockIdx.z ? Wout : Wq;
    unsigned short* dst = blockIdx.z ? WoutT : WqT;
    const int r0 = blockIdx.x * 64;   // src row tile
    const int c0 = blockIdx.y * 64;   // src col tile
    __shared__ float T[64][65];
    const int tid = threadIdx.x;
    const int r = tid >> 4, c4 = (tid & 15) * 4;
    for (int rr = 0; rr < 64; rr += 16) {
        float4 v = *(const float4*)(src + (size_t)(r0 + rr + r) * DQ + c0 + c4);
        T[rr + r][c4 + 0] = v.x; T[rr + r][c4 + 1] = v.y;
        T[rr + r][c4 + 2] = v.z; T[rr + r][c4 + 3] = v.w;
    }
    __syncthreads();
    for (int rr = 0; rr < 64; rr += 16) {
        int dr = rr + r;
        ushort4 w;
        w.x = f2bf(T[c4 + 0][dr]); w.y = f2bf(T[c4 + 1][dr]);
        w.z = f2bf(T[c4 + 2][dr]); w.w = f2bf(T[c4 + 3][dr]);
        *(ushort4*)(dst + (size_t)(c0 + dr) * DQ + r0 + c4) = w;
    }
}

// ---------------------------------------------------------------------------
// kv = tokens @ Wkv  (f32, small: 1.2 GF)
// ---------------------------------------------------------------------------
__global__ __launch_bounds__(256) void gemm_kv_k(const float* __restrict__ tokens,
                                                 const float* __restrict__ Wkv,
                                                 float* __restrict__ kv_out) {
    const int b = blockIdx.z;
    const int j0 = blockIdx.x * 64;
    __shared__ float As[16][64];
    __shared__ float Bs[16][64];
    const int tid = threadIdx.x;
    const int tx = tid & 15, ty = tid >> 4;
    float acc[4][4] = {};
    const float* tb = tokens + (size_t)b * NT * DKV;
    for (int c0 = 0; c0 < DKV; c0 += 16) {
        {
            int m = tid >> 2, jq = tid & 3;
            float4 v = *(const float4*)(tb + (size_t)m * DKV + c0 + jq * 4);
            As[jq * 4 + 0][m] = v.x; As[jq * 4 + 1][m] = v.y;
            As[jq * 4 + 2][m] = v.z; As[jq * 4 + 3][m] = v.w;
            int kk = tid >> 4, n4 = (tid & 15) * 4;
            *(float4*)&Bs[kk][n4] = *(const float4*)(Wkv + (size_t)(c0 + kk) * (2 * DQ) + j0 + n4);
        }
        __syncthreads();
#pragma unroll
        for (int kk = 0; kk < 16; ++kk) {
            float a[4], bb[4];
            *(float4*)a  = *(float4*)&As[kk][ty * 4];
            *(float4*)bb = *(float4*)&Bs[kk][tx * 4];
#pragma unroll
            for (int i = 0; i < 4; ++i)
#pragma unroll
                for (int j = 0; j < 4; ++j)
                    acc[i][j] += a[i] * bb[j];
        }
        __syncthreads();
    }
    float* ob = kv_out + (size_t)b * NT * (2 * DQ);
#pragma unroll
    for (int i = 0; i < 4; ++i)
        *(float4*)(ob + (size_t)(ty * 4 + i) * (2 * DQ) + j0 + tx * 4) = *(float4*)acc[i];
}

// ---------------------------------------------------------------------------
// MFMA GEMM with counted-vmcnt pipeline (T4): 3 LDS buffers, prefetch depth 2,
// raw s_barrier (NO vmcnt(0) drain in-loop). Each STAGE = 4 global_load_lds
// per thread; steady state 8 outstanding; vmcnt(4) drains exactly the
// oldest tile's loads while the next tile's stay in flight.
// q[b][n][j] = featT[b][n][:] . WqT[j][:]
// ---------------------------------------------------------------------------
__global__ __launch_bounds__(256) void gemm_q_mfma(const unsigned short* __restrict__ At,
                                                   const unsigned short* __restrict__ Bt,
                                                   unsigned short* __restrict__ C) {
    const int b = blockIdx.z;
    const int m0 = blockIdx.x * 128;
    const int n0 = blockIdx.y * 128;
    __shared__ __align__(16) unsigned short ldsA[3][128 * 32];
    __shared__ __align__(16) unsigned short ldsB[3][128 * 32];
    const int tid = threadIdx.x;
    const int lane = tid & 63;
    const int wm = ((tid >> 7) & 1) * 64;      // wave m offset
    const int wn = ((tid >> 6) & 1) * 64;      // wave n offset
    const int fr = lane & 15;
    const int fg = lane >> 4;
    const int pslot = (fg ^ ((fr >> 1) & 3)) * 16;   // physical 16B slot for frag reads
    const int wbase = (tid & 192) * 16;              // wave-uniform LDS byte base
    f32x4 acc[4][4] = {};

    const unsigned short* Ab = At + (size_t)b * NQ * DQ + (size_t)m0 * DQ;
    const unsigned short* Bb = Bt + (size_t)n0 * DQ;
    const int srow_lo = tid >> 2;
    const int sslot = tid & 3;

    auto STAGE = [&](int buf, int k0) {
#pragma unroll
        for (int i = 0; i < 2; ++i) {
            int row = i * 64 + srow_lo;
            int sl = sslot ^ ((row >> 1) & 3);
            gload_lds16(Ab + (size_t)row * DQ + k0 + sl * 8,
                        (char*)ldsA[buf] + i * 4096 + wbase);
            gload_lds16(Bb + (size_t)row * DQ + k0 + sl * 8,
                        (char*)ldsB[buf] + i * 4096 + wbase);
        }
    };

    const int NSTEP = DQ / 32;   // 24
    STAGE(0, 0);
    STAGE(1, 32);                // 8 outstanding/thread
    int cur = 0;
    for (int t = 0; t < NSTEP; ++t) {
        if (t + 1 < NSTEP) {
            asm volatile("s_waitcnt vmcnt(4)" ::: "memory");   // tile t ready, t+1 in flight
        } else {
            asm volatile("s_waitcnt vmcnt(0)" ::: "memory");   // last tile
        }
        __builtin_amdgcn_s_barrier();
        __builtin_amdgcn_sched_barrier(0);
        int nxt = cur + 2; if (nxt >= 3) nxt -= 3;
        if (t + 2 < NSTEP) STAGE(nxt, (t + 2) * 32);           // overwrite buf of tile t-1 (all waves past it)
        bf16x8 af[4], bfr[4];
#pragma unroll
        for (int f = 0; f < 4; ++f) {
            af[f]  = *(const bf16x8*)((const char*)ldsA[cur] + (wm + f * 16 + fr) * 64 + pslot);
            bfr[f] = *(const bf16x8*)((const char*)ldsB[cur] + (wn + f * 16 + fr) * 64 + pslot);
        }
#pragma unroll
        for (int i = 0; i < 4; ++i)
#pragma unroll
            for (int j = 0; j < 4; ++j)
                acc[i][j] = __builtin_amdgcn_mfma_f32_16x16x32_bf16(af[i], bfr[j], acc[i][j], 0, 0, 0);
        cur = cur + 1; if (cur >= 3) cur = 0;
    }
    // C/D layout: col = lane&15, row = (lane>>4)*4 + reg   [m89/m91]
    unsigned short* Cb = C + (size_t)b * NQ * DQ;
#pragma unroll
    for (int i = 0; i < 4; ++i)
#pragma unroll
        for (int j = 0; j < 4; ++j) {
            int rbase = m0 + wm + i * 16 + fg * 4;
            int col = n0 + wn + j * 16 + fr;
#pragma unroll
            for (int r = 0; r < 4; ++r)
                Cb[(size_t)(rbase + r) * DQ + col] = f2bf(acc[i][j][r]);
        }
}

// ---------------------------------------------------------------------------
// MFMA GEMM (transposed output, fused residual+bias), counted-vmcnt pipeline:
// out[b][d][n] = WoutT[d][:] . ao[b][n][:] + feat[b][d][n] + bout[d]
// ---------------------------------------------------------------------------
__global__ __launch_bounds__(256) void gemm_out_mfma(const unsigned short* __restrict__ At,
                                                     const unsigned short* __restrict__ Bt,
                                                     const float* __restrict__ feat,
                                                     const float* __restrict__ bout,
                                                     float* __restrict__ out) {
    const int b = blockIdx.z;
    const int m0 = blockIdx.x * 128;   // d
    const int n0 = blockIdx.y * 128;   // n
    __shared__ __align__(16) unsigned short ldsA[3][128 * 32];
    __shared__ __align__(16) unsigned short ldsB[3][128 * 32];
    const int tid = threadIdx.x;
    const int lane = tid & 63;
    const int wm = ((tid >> 7) & 1) * 64;
    const int wn = ((tid >> 6) & 1) * 64;
    const int fr = lane & 15;
    const int fg = lane >> 4;
    const int pslot = (fg ^ ((fr >> 1) & 3)) * 16;
    const int wbase = (tid & 192) * 16;
    f32x4 acc[4][4] = {};

    const unsigned short* Ab = At + (size_t)m0 * DQ;                          // WoutT (shared across b)
    const unsigned short* Bb = Bt + (size_t)b * NQ * DQ + (size_t)n0 * DQ;    // ao
    const int srow_lo = tid >> 2;
    const int sslot = tid & 3;

    auto STAGE = [&](int buf, int k0) {
#pragma unroll
        for (int i = 0; i < 2; ++i) {
            int row = i * 64 + srow_lo;
            int sl = sslot ^ ((row >> 1) & 3);
            gload_lds16(Ab + (size_t)row * DQ + k0 + sl * 8,
                        (char*)ldsA[buf] + i * 4096 + wbase);
            gload_lds16(Bb + (size_t)row * DQ + k0 + sl * 8,
                        (char*)ldsB[buf] + i * 4096 + wbase);
        }
    };

    const int NSTEP = DQ / 32;   // 24
    STAGE(0, 0);
    STAGE(1, 32);
    int cur = 0;
    for (int t = 0; t < NSTEP; ++t) {
        if (t + 1 < NSTEP) {
            asm volatile("s_waitcnt vmcnt(4)" ::: "memory");
        } else {
            asm volatile("s_waitcnt vmcnt(0)" ::: "memory");
        }
        __builtin_amdgcn_s_barrier();
        __builtin_amdgcn_sched_barrier(0);
        int nxt = cur + 2; if (nxt >= 3) nxt -= 3;
        if (t + 2 < NSTEP) STAGE(nxt, (t + 2) * 32);
        bf16x8 af[4], bfr[4];
#pragma unroll
        for (int f = 0; f < 4; ++f) {
            af[f]  = *(const bf16x8*)((const char*)ldsA[cur] + (wm + f * 16 + fr) * 64 + pslot);
            bfr[f] = *(const bf16x8*)((const char*)ldsB[cur] + (wn + f * 16 + fr) * 64 + pslot);
        }
#pragma unroll
        for (int i = 0; i < 4; ++i)
#pragma unroll
            for (int j = 0; j < 4; ++j)
                acc[i][j] = __builtin_amdgcn_mfma_f32_16x16x32_bf16(af[i], bfr[j], acc[i][j], 0, 0, 0);
        cur = cur + 1; if (cur >= 3) cur = 0;
    }
    float* ob = out + (size_t)b * DQ * NQ;
    const float* fb = feat + (size_t)b * DQ * NQ;
#pragma unroll
    for (int i = 0; i < 4; ++i)
#pragma unroll
        for (int j = 0; j < 4; ++j) {
            int dbase = m0 + wm + i * 16 + fg * 4;
            int n = n0 + wn + j * 16 + fr;
#pragma unroll
            for (int r = 0; r < 4; ++r) {
                int d = dbase + r;
                size_t idx = (size_t)d * NQ + n;
                ob[idx] = acc[i][j][r] + fb[idx] + bout[d];
            }
        }
}

// ---------------------------------------------------------------------------
// MFMA attention per (b, h, 256 q-rows). K staged with fused RoPE (bf16),
// V staged transposed (bf16); both held as register fragments per wave.
// Q frags loaded straight from global, RoPE'd in-register with 1/8 scale
// folded in. P/out bounce through a wave-private LDS tile (no barriers in
// main loop). Writes ao (bf16) IN PLACE over q.
// ---------------------------------------------------------------------------
__global__ __launch_bounds__(256) void attn_mfma(const float* __restrict__ kv,
                                                 unsigned short* __restrict__ q) {
    const int qb = blockIdx.x, h = blockIdx.y, b = blockIdx.z;
    const int n0 = qb * 256;
    __shared__ __align__(16) unsigned short Ks[64][72];   // RoPE'd K, [t][d]
    __shared__ __align__(16) unsigned short VT[64][72];   // V^T, [d][t]
    __shared__ __align__(16) unsigned short Ps[4][16][72];// per-wave P/out bounce
    const int tid = threadIdx.x;
    const int lane = tid & 63;
    const int wid = tid >> 6;
    const int fr = lane & 15;   // frag row/col index
    const int fg = lane >> 4;   // frag k-group

    // ---- stage K with RoPE ----
    {
        const int t = tid >> 2, dg = (tid & 3) * 8;
        const float* krow = kv + ((size_t)b * NT + t) * (2 * DQ) + h * HD;
        float lo[8], hi[8];
        *(float4*)&lo[0] = *(const float4*)(krow + dg);
        *(float4*)&lo[4] = *(const float4*)(krow + dg + 4);
        *(float4*)&hi[0] = *(const float4*)(krow + dg + 32);
        *(float4*)&hi[4] = *(const float4*)(krow + dg + 36);
        union { bf16x8 v; unsigned short u[8]; } plo, phi;
#pragma unroll
        for (int e = 0; e < 8; ++e) {
            float inv = exp2f((float)(dg + e) * -0.41524101186092029f);  // -log2(1e4)/32
            float s, c; __sincosf((float)t * inv, &s, &c);
            plo.u[e] = f2bf(lo[e] * c - hi[e] * s);
            phi.u[e] = f2bf(hi[e] * c + lo[e] * s);
        }
        *(bf16x8*)&Ks[t][dg]      = plo.v;
        *(bf16x8*)&Ks[t][dg + 32] = phi.v;
    }
    // ---- stage V transposed ----
    {
        const int t = tid >> 2, d0 = (tid & 3) * 16;
        const float* vrow = kv + ((size_t)b * NT + t) * (2 * DQ) + DQ + h * HD + d0;
        float vv[16];
        *(float4*)&vv[0]  = *(const float4*)(vrow + 0);
        *(float4*)&vv[4]  = *(const float4*)(vrow + 4);
        *(float4*)&vv[8]  = *(const float4*)(vrow + 8);
        *(float4*)&vv[12] = *(const float4*)(vrow + 12);
#pragma unroll
        for (int dd = 0; dd < 16; ++dd)
            VT[d0 + dd][t] = f2bf(vv[dd]);
    }
    __syncthreads();

    // ---- K, V fragments to registers (held for whole kernel) ----
    bf16x8 kf[4][2], vf[4][2];
#pragma unroll
    for (int j = 0; j < 4; ++j)
#pragma unroll
        for (int hh = 0; hh < 2; ++hh) {
            kf[j][hh] = *(const bf16x8*)&Ks[j * 16 + fr][hh * 32 + fg * 8];
            vf[j][hh] = *(const bf16x8*)&VT[j * 16 + fr][hh * 32 + fg * 8];
        }

    // per-lane RoPE inv-freqs for q frag elements (d = fg*8+e, d<32 half)
    float invf[8];
#pragma unroll
    for (int e = 0; e < 8; ++e)
        invf[e] = exp2f((float)(fg * 8 + e) * -0.41524101186092029f);

    unsigned short* qbase = q + ((size_t)b * NQ + n0) * DQ + h * HD;

    for (int rt = wid; rt < 16; rt += 4) {
        const int row = rt * 16 + fr;
        const unsigned short* qrow = qbase + (size_t)row * DQ + fg * 8;
        bf16x8 q0 = *(const bf16x8*)qrow;          // d = fg*8..+8
        bf16x8 q1 = *(const bf16x8*)(qrow + 32);   // d+32
        union { bf16x8 v; unsigned short u[8]; } qa, qb2;
        const float pos = (float)(n0 + row);
#pragma unroll
        for (int e = 0; e < 8; ++e) {
            float s, c; __sincosf(pos * invf[e], &s, &c);
            float v0 = bf2f((unsigned short)q0[e]);
            float v1 = bf2f((unsigned short)q1[e]);
            qa.u[e]  = f2bf((v0 * c - v1 * s) * 0.125f);   // fold hd^-0.5
            qb2.u[e] = f2bf((v1 * c + v0 * s) * 0.125f);
        }
        // S = Q K^T : 4 col-tiles x 2 k-halves
        f32x4 sc[4];
#pragma unroll
        for (int j = 0; j < 4; ++j) {
            f32x4 z = {};
            sc[j] = __builtin_amdgcn_mfma_f32_16x16x32_bf16(qa.v, kf[j][0], z, 0, 0, 0);
            sc[j] = __builtin_amdgcn_mfma_f32_16x16x32_bf16(qb2.v, kf[j][1], sc[j], 0, 0, 0);
        }
        // softmax over t: lane holds S[q=(fg*4+r)][t=j*16+fr]; reduce over fr
#pragma unroll
        for (int r = 0; r < 4; ++r) {
            float m = fmaxf(fmaxf(sc[0][r], sc[1][r]), fmaxf(sc[2][r], sc[3][r]));
            for (int off = 1; off < 16; off <<= 1) m = fmaxf(m, __shfl_xor(m, off));
            float s = 0.f;
#pragma unroll
            for (int j = 0; j < 4; ++j) { float p = __expf(sc[j][r] - m); sc[j][r] = p; s += p; }
            for (int off = 1; off < 16; off <<= 1) s += __shfl_xor(s, off);
            float is = 1.0f / s;
#pragma unroll
            for (int j = 0; j < 4; ++j) sc[j][r] *= is;
        }
        // P scatter (D-layout) -> LDS -> reload as A-frags
#pragma unroll
        for (int r = 0; r < 4; ++r)
#pragma unroll
            for (int j = 0; j < 4; ++j)
                Ps[wid][fg * 4 + r][j * 16 + fr] = f2bf(sc[j][r]);
        bf16x8 pa0 = *(const bf16x8*)&Ps[wid][fr][fg * 8];
        bf16x8 pa1 = *(const bf16x8*)&Ps[wid][fr][32 + fg * 8];
        // out = P V : 4 d-tiles x 2 t-halves; scatter result into same LDS tile
#pragma unroll
        for (int n = 0; n < 4; ++n) {
            f32x4 z = {};
            f32x4 o = __builtin_amdgcn_mfma_f32_16x16x32_bf16(pa0, vf[n][0], z, 0, 0, 0);
            o = __builtin_amdgcn_mfma_f32_16x16x32_bf16(pa1, vf[n][1], o, 0, 0, 0);
#pragma unroll
            for (int r = 0; r < 4; ++r)
                Ps[wid][fg * 4 + r][n * 16 + fr] = f2bf(o[r]);
        }
        // coalesced writeback (in place over q)
#pragma unroll
        for (int p = 0; p < 2; ++p) {
            int rr = p * 8 + (lane >> 3), ch = lane & 7;
            bf16x8 ov = *(const bf16x8*)&Ps[wid][rr][ch * 8];
            *(bf16x8*)(qbase + (size_t)(rt * 16 + rr) * DQ + ch * 8) = ov;
        }
    }
}

// ---------------------------------------------------------------------------
extern "C" void kernel_launch(void* const* d_in, const int* in_sizes, int n_in,
                              void* d_out, int out_size, void* d_ws, size_t ws_size,
                              hipStream_t stream) {
    const float* feat   = (const float*)d_in[0];
    const float* tokens = (const float*)d_in[1];
    const float* Wq     = (const float*)d_in[2];
    const float* Wkv    = (const float*)d_in[3];
    const float* Wout   = (const float*)d_in[4];
    const float* bout   = (const float*)d_in[5];
    float* out = (float*)d_out;

    float* ws_kv = (float*)d_ws;                                        // [B][NT][2*DQ] f32
    unsigned short* ws_featT = (unsigned short*)(ws_kv + (size_t)BATCH * NT * 2 * DQ);  // [B][NQ][DQ] bf16
    unsigned short* ws_q     = ws_featT + (size_t)BATCH * NQ * DQ;      // [B][NQ][DQ] bf16 (q, then ao in place)
    unsigned short* ws_WqT   = ws_q + (size_t)BATCH * NQ * DQ;          // [DQ][DQ] bf16
    unsigned short* ws_WoutT = ws_WqT + (size_t)DQ * DQ;                // [DQ][DQ] bf16

    conv_w_k<<<dim3(12, 12, 2), 256, 0, stream>>>(Wq, Wout, ws_WqT, ws_WoutT);
    conv_feat_k<<<dim3(16, 12, BATCH), 256, 0, stream>>>(feat, ws_featT);
    gemm_kv_k<<<dim3(24, 1, BATCH), 256, 0, stream>>>(tokens, Wkv, ws_kv);
    gemm_q_mfma<<<dim3(8, 6, BATCH), 256, 0, stream>>>(ws_featT, ws_WqT, ws_q);
    attn_mfma<<<dim3(4, 12, BATCH), 256, 0, stream>>>(ws_kv, ws_q);
    gemm_out_mfma<<<dim3(6, 8, BATCH), 256, 0, stream>>>(ws_WoutT, ws_q, feat, bout, out);
}